// Round 2
// baseline (403.249 us; speedup 1.0000x reference)
//
#include <hip/hip_runtime.h>
#include <stdint.h>

#define NB   8
#define NPTS 8192
#define NS   1024
#define NK   16
#define NH   192
#define HROW 200   // padded LDS row length in bf16 elems (400 B = 25*16B, stride ≡4 mod 32 dwords)

typedef float    f32x4 __attribute__((ext_vector_type(4)));
typedef short    s16x8 __attribute__((ext_vector_type(8)));
typedef uint32_t u32;
typedef unsigned long long u64;

// round-to-nearest-even f32 -> bf16 (matches numpy/jax RNE; output is internal only)
__device__ __forceinline__ uint16_t f2bf(float f) {
  u32 u = __float_as_uint(f);
  return (uint16_t)((u + 0x7FFFu + ((u >> 16) & 1u)) >> 16);
}

// ---------------- kernel A: transpose + bf16-convert weights (once, tiny) ----------------
// wT[n][k] = bf16(w[k][n]) so MFMA B-fragments (8 consecutive k per lane) are contiguous.
__global__ void prep_weights(const float* __restrict__ w1, const float* __restrict__ w2,
                             uint16_t* __restrict__ wT1, uint16_t* __restrict__ wT2) {
  int e = blockIdx.x * 256 + threadIdx.x;
  if (e < NH * NH) {
    int n = e / NH, k = e % NH;
    wT1[n * NH + k] = f2bf(w1[k * NH + n]);
    wT2[n * NH + k] = f2bf(w2[k * NH + n]);
  }
}

// ---------------- kernel B: exact top-16 NN per supernode ----------------
// Wave per supernode. Distances computed bit-identically to numpy f32
// (((dx^2+dy^2)+dz^2), no fma contraction). Selection key = (bits(d)<<32)|idx:
// u64 order == (distance, index) lexicographic — exact stable-top_k tie semantics.
// Wave-shared top-16 kept SORTED ACROSS LANES 0..15 (lane j = rank j); insert =
// rank by ballot + shfl_up shift. Expected ~116 inserts per 8192-candidate stream.
__global__ void __launch_bounds__(256) knn_kernel(const float* __restrict__ pts,
                                                  const int* __restrict__ sidx,
                                                  int* __restrict__ nbr) {
  extern __shared__ char dynsmem[];
  float* X = (float*)dynsmem;
  float* Y = X + NPTS;
  float* Z = Y + NPTS;
  const int b = blockIdx.x >> 5;       // 32 blocks per sample
  const int chunk = blockIdx.x & 31;
  const float* pb = pts + (size_t)b * NPTS * 3;
  for (int j = threadIdx.x; j < NPTS; j += 256) {
    X[j] = pb[3 * j + 0];
    Y[j] = pb[3 * j + 1];
    Z[j] = pb[3 * j + 2];
  }
  __syncthreads();
  const int wave = threadIdx.x >> 6, lane = threadIdx.x & 63;
  for (int q = 0; q < 8; ++q) {
    int s = chunk * 32 + wave * 8 + q;
    int si = sidx[b * NS + s];
    float sx = X[si], sy = Y[si], sz = Z[si];   // LDS broadcast (uniform addr)
    u64 arr = ~0ull;                            // lane j<16: rank-j key; others: +inf
    u64 T   = ~0ull;                            // current 16th-smallest key
    float Td = __uint_as_float(0x7F800000u);    // its distance part (+inf)
    for (int t = 0; t < NPTS / 64; ++t) {
      int j = t * 64 + lane;
      float dx = X[j] - sx, dy = Y[j] - sy, dz = Z[j] - sz;
      float d = __fadd_rn(__fadd_rn(__fmul_rn(dx, dx), __fmul_rn(dy, dy)),
                          __fmul_rn(dz, dz));
      u64 ball = __ballot(d <= Td);             // superset test (f32-cheap); exact check below
      if (ball) {                                // wave-uniform branch
        u64 key = ((u64)__float_as_uint(d) << 32) | (u32)j;
        do {
          int src = __builtin_ctzll(ball);
          ball &= ball - 1;
          u64 k2 = __shfl(key, src);
          if (k2 < T) {                          // exact (dist,idx) compare, uniform
            int r = __popcll(__ballot(arr < k2));    // rank of new key
            u64 up = __shfl_up(arr, 1);
            if (lane == r) arr = k2;
            else if (lane > r && lane < 16) arr = up;
            T = __shfl(arr, 15);
            Td = __uint_as_float((u32)(T >> 32));
          }
        } while (ball);
      }
    }
    if (lane < 16) nbr[(b * NS + s) * NK + lane] = (int)(u32)arr;
  }
}

// ---------------- kernel C: fused gather + sincos embed + MLP (bf16 MFMA) + mean-pool ----
__device__ __forceinline__ float h0val(int c, float c0, float c1, float c2,
                                       const float* __restrict__ w_in,
                                       const float* __restrict__ b_in) {
  int dd = c >> 6;                 // which coordinate (64 channels each)
  int i  = c & 63;                 // [0,32): sin, [32,64): cos
  float coord = (dd == 0) ? c0 : ((dd == 1) ? c1 : c2);
  // omega_m = 10000^(-m/32) = exp2(-m*log2(1e4)/32)
  float om = exp2f((float)(i & 31) * -0.41524101186092029f);
  float arg = coord * om;
  float e = (i < 32) ? __sinf(arg) : __cosf(arg);
  float acc = b_in[c] + e;
  acc = __fmaf_rn(c2, w_in[2 * NH + c], acc);
  acc = __fmaf_rn(c1, w_in[1 * NH + c], acc);
  acc = __fmaf_rn(c0, w_in[0 * NH + c], acc);
  return acc;
}

__device__ __forceinline__ float gelu_tanh(float x) {
  float u = 0.7978845608028654f * __fmaf_rn(0.044715f * x, x * x, x);
  float t = 1.0f - 2.0f / (__expf(2.0f * u) + 1.0f);   // tanh(u)
  return 0.5f * x * (1.0f + t);
}

__device__ __forceinline__ void stage_w(uint16_t* wb, const uint16_t* __restrict__ wT, int tid) {
  const uint4* src = (const uint4*)wT;     // 192 rows * 24 chunks of 16B = 4608
  #pragma unroll
  for (int it = 0; it < 18; ++it) {
    int cc = it * 256 + tid;
    int n = cc / 24, p = cc % 24;
    *(uint4*)(wb + n * HROW + p * 8) = src[cc];
  }
}

__device__ __forceinline__ void gemm192(f32x4 acc[8][3], const uint16_t* __restrict__ hb,
                                        const uint16_t* __restrict__ wb, int wave, int lane) {
  const int lrow = lane & 15, lg = lane >> 4;
  #pragma unroll
  for (int kk = 0; kk < 6; ++kk) {
    int koff = kk * 32 + lg * 8;
    s16x8 a[8], bf[3];
    #pragma unroll
    for (int mt = 0; mt < 8; ++mt)
      a[mt] = __builtin_bit_cast(s16x8, *(const uint4*)(hb + (mt * 16 + lrow) * HROW + koff));
    #pragma unroll
    for (int nt = 0; nt < 3; ++nt)
      bf[nt] = __builtin_bit_cast(s16x8, *(const uint4*)(wb + (wave * 48 + nt * 16 + lrow) * HROW + koff));
    #pragma unroll
    for (int mt = 0; mt < 8; ++mt)
      #pragma unroll
      for (int nt = 0; nt < 3; ++nt)
        acc[mt][nt] = __builtin_amdgcn_mfma_f32_16x16x32_bf16(a[mt], bf[nt], acc[mt][nt], 0, 0, 0);
  }
}

__global__ void __launch_bounds__(256) mlp_kernel(
    const float* __restrict__ pts, const int* __restrict__ nbr,
    const float* __restrict__ w_in, const float* __restrict__ b_in,
    const float* __restrict__ b1v, const float* __restrict__ b2v,
    const uint16_t* __restrict__ wT1, const uint16_t* __restrict__ wT2,
    float* __restrict__ out) {
  extern __shared__ char dynsmem[];
  uint16_t* hbuf = (uint16_t*)dynsmem;       // [128][HROW] bf16 (h0, then h1)
  uint16_t* wbuf = hbuf + 128 * HROW;        // [192][HROW] bf16 (wT1, then wT2)
  const int g = blockIdx.x, tid = threadIdx.x;
  const int wave = tid >> 6, lane = tid & 63;

  stage_w(wbuf, wT1, tid);

  { // h0 = nbr@w_in + b_in + sincos  (2 threads per row, 96 cols each, paired b32 writes)
    int r = tid >> 1, half = tid & 1;
    int grow = g * 128 + r;                  // = (b*1024+s)*16 + k
    int b = grow >> 14;
    int pidx = nbr[grow];
    const float* pp = pts + ((size_t)b * NPTS + pidx) * 3;
    float c0 = pp[0], c1 = pp[1], c2 = pp[2];
    for (int jj = 0; jj < 48; ++jj) {
      int c = half * 96 + jj * 2;
      float v0 = h0val(c,     c0, c1, c2, w_in, b_in);
      float v1 = h0val(c + 1, c0, c1, c2, w_in, b_in);
      u32 pk = (u32)f2bf(v0) | ((u32)f2bf(v1) << 16);
      *(u32*)(hbuf + r * HROW + c) = pk;
    }
  }
  __syncthreads();

  f32x4 acc[8][3] = {};
  gemm192(acc, hbuf, wbuf, wave, lane);      // h0 @ w1
  __syncthreads();                            // all reads of hbuf/wbuf done

  { // epilogue 1: +b1, gelu, write h1 (bf16) back into hbuf
    const int lrow = lane & 15, lg = lane >> 4;
    #pragma unroll
    for (int nt = 0; nt < 3; ++nt) {
      int col = wave * 48 + nt * 16 + lrow;
      float bb = b1v[col];
      #pragma unroll
      for (int mt = 0; mt < 8; ++mt) {
        #pragma unroll
        for (int j = 0; j < 4; ++j) {
          int row = mt * 16 + lg * 4 + j;     // verified C/D layout
          hbuf[row * HROW + col] = f2bf(gelu_tanh(acc[mt][nt][j] + bb));
        }
      }
    }
  }
  stage_w(wbuf, wT2, tid);
  __syncthreads();

  f32x4 acc2[8][3] = {};
  gemm192(acc2, hbuf, wbuf, wave, lane);     // h1 @ w2

  { // epilogue 2: mean over the 16 rows of each C-tile (= one supernode) + b2
    const int lrow = lane & 15;
    #pragma unroll
    for (int mt = 0; mt < 8; ++mt) {
      #pragma unroll
      for (int nt = 0; nt < 3; ++nt) {
        float ssum = acc2[mt][nt][0] + acc2[mt][nt][1] + acc2[mt][nt][2] + acc2[mt][nt][3];
        ssum += __shfl_xor(ssum, 16);
        ssum += __shfl_xor(ssum, 32);
        if (lane < 16) {
          int col = wave * 48 + nt * 16 + lrow;
          out[(size_t)(g * 8 + mt) * NH + col] = ssum * 0.0625f + b2v[col];
        }
      }
    }
  }
}

extern "C" void kernel_launch(void* const* d_in, const int* in_sizes, int n_in,
                              void* d_out, int out_size, void* d_ws, size_t ws_size,
                              hipStream_t stream) {
  (void)in_sizes; (void)n_in; (void)out_size; (void)ws_size;
  const float* pts  = (const float*)d_in[0];
  const int*   sidx = (const int*)d_in[1];
  const float* w_in = (const float*)d_in[2];
  const float* b_in = (const float*)d_in[3];
  const float* w1   = (const float*)d_in[4];
  const float* b1   = (const float*)d_in[5];
  const float* w2   = (const float*)d_in[6];
  const float* b2   = (const float*)d_in[7];
  float* out = (float*)d_out;

  int* nbr = (int*)d_ws;                                        // 131072 ints = 512 KB
  uint16_t* wT1 = (uint16_t*)((char*)d_ws + (size_t)NB * NS * NK * 4);
  uint16_t* wT2 = wT1 + NH * NH;                                // +72 KB each

  hipLaunchKernelGGL(prep_weights, dim3(144), dim3(256), 0, stream, w1, w2, wT1, wT2);

  (void)hipFuncSetAttribute((const void*)knn_kernel,
        hipFuncAttributeMaxDynamicSharedMemorySize, NPTS * 3 * 4);
  hipLaunchKernelGGL(knn_kernel, dim3(NB * 32), dim3(256), NPTS * 3 * 4, stream,
                     pts, sidx, nbr);

  const int lds_c = (128 + 192) * HROW * 2;   // 128000 B
  (void)hipFuncSetAttribute((const void*)mlp_kernel,
        hipFuncAttributeMaxDynamicSharedMemorySize, lds_c);
  hipLaunchKernelGGL(mlp_kernel, dim3(NB * NS / 8), dim3(256), lds_c, stream,
                     pts, nbr, w_in, b_in, b1, b2, wT1, wT2, out);
}

// Round 3
// 401.622 us; speedup vs baseline: 1.0040x; 1.0040x over previous
//
#include <hip/hip_runtime.h>
#include <stdint.h>

#define NB   8
#define NPTS 8192
#define NS   1024
#define NK   16
#define NH   192
#define HROW 200   // padded LDS row length in bf16 elems (400 B = 25*16B, stride ≡4 mod 32 dwords)

typedef float    f32x4 __attribute__((ext_vector_type(4)));
typedef short    s16x8 __attribute__((ext_vector_type(8)));
typedef uint32_t u32;
typedef unsigned long long u64;

// round-to-nearest-even f32 -> bf16 (matches numpy/jax RNE; output is internal only)
__device__ __forceinline__ uint16_t f2bf(float f) {
  u32 u = __float_as_uint(f);
  return (uint16_t)((u + 0x7FFFu + ((u >> 16) & 1u)) >> 16);
}

// ---------------- kernel A: transpose + bf16-convert weights (once, tiny) ----------------
__global__ void prep_weights(const float* __restrict__ w1, const float* __restrict__ w2,
                             uint16_t* __restrict__ wT1, uint16_t* __restrict__ wT2) {
  int e = blockIdx.x * 256 + threadIdx.x;
  if (e < NH * NH) {
    int n = e / NH, k = e % NH;
    wT1[n * NH + k] = f2bf(w1[k * NH + n]);
    wT2[n * NH + k] = f2bf(w2[k * NH + n]);
  }
}

// ---------------- kernel B: exact top-16 NN, 8 queries per wave CONCURRENTLY ----------------
// One LDS point-load feeds 8 query-distance computations (amortizes the
// 1-wave/SIMD LDS latency that made v1 300us). Distances bit-identical to numpy
// f32 (((dx^2+dy^2)+dz^2), no fma). Selection key = (bits(d)<<32)|idx: u64 order
// == (distance,index) lexicographic — exact stable-top_k tie semantics.
// Per query, wave-shared top-16 SORTED ACROSS LANES 0..15 (lane j = rank j).
__global__ void __launch_bounds__(256) knn_kernel(const float* __restrict__ pts,
                                                  const int* __restrict__ sidx,
                                                  int* __restrict__ nbr) {
  extern __shared__ char dynsmem[];
  float* X = (float*)dynsmem;
  float* Y = X + NPTS;
  float* Z = Y + NPTS;
  const int b = blockIdx.x >> 5;       // 32 blocks per sample
  const int chunk = blockIdx.x & 31;
  const float* pb = pts + (size_t)b * NPTS * 3;
  for (int j = threadIdx.x; j < NPTS; j += 256) {
    X[j] = pb[3 * j + 0];
    Y[j] = pb[3 * j + 1];
    Z[j] = pb[3 * j + 2];
  }
  __syncthreads();
  const int wave = threadIdx.x >> 6, lane = threadIdx.x & 63;
  const int sbase = chunk * 32 + wave * 8;

  float sx[8], sy[8], sz[8], Td[8];
  u64 arr[8], T[8];
  #pragma unroll
  for (int q = 0; q < 8; ++q) {
    int si = sidx[b * NS + sbase + q];
    sx[q] = X[si]; sy[q] = Y[si]; sz[q] = Z[si];   // LDS broadcast (uniform addr)
    arr[q] = ~0ull;                                 // lane j<16: rank-j key
    T[q]   = ~0ull;                                 // 16th-smallest key
    Td[q]  = __uint_as_float(0x7F800000u);          // its distance part (+inf)
  }

  for (int t = 0; t < NPTS / 64; ++t) {
    int j = t * 64 + lane;
    float x = X[j], y = Y[j], z = Z[j];
    #pragma unroll
    for (int q = 0; q < 8; ++q) {
      float dx = x - sx[q], dy = y - sy[q], dz = z - sz[q];
      float d = __fadd_rn(__fadd_rn(__fmul_rn(dx, dx), __fmul_rn(dy, dy)),
                          __fmul_rn(dz, dz));
      u64 ball = __ballot(d <= Td[q]);          // superset test; exact check below
      if (ball) {                                // wave-uniform branch (rare after warmup)
        u64 key = ((u64)__float_as_uint(d) << 32) | (u32)j;
        do {
          int src = __builtin_ctzll(ball);
          ball &= ball - 1;
          u64 k2 = __shfl(key, src);
          if (k2 < T[q]) {                       // exact (dist,idx) compare, uniform
            int r = __popcll(__ballot(arr[q] < k2));   // rank of new key
            u64 up = __shfl_up(arr[q], 1);
            if (lane == r) arr[q] = k2;
            else if (lane > r && lane < 16) arr[q] = up;
            T[q] = __shfl(arr[q], 15);
            Td[q] = __uint_as_float((u32)(T[q] >> 32));
          }
        } while (ball);
      }
    }
  }
  #pragma unroll
  for (int q = 0; q < 8; ++q)
    if (lane < 16) nbr[(b * NS + sbase + q) * NK + lane] = (int)(u32)arr[q];
}

// ---------------- kernel C: fused gather + sincos embed + MLP (bf16 MFMA) + mean-pool ----
__device__ __forceinline__ float h0val(int c, float c0, float c1, float c2,
                                       const float* __restrict__ w_in,
                                       const float* __restrict__ b_in) {
  int dd = c >> 6;                 // which coordinate (64 channels each)
  int i  = c & 63;                 // [0,32): sin, [32,64): cos
  float coord = (dd == 0) ? c0 : ((dd == 1) ? c1 : c2);
  float om = exp2f((float)(i & 31) * -0.41524101186092029f);
  float arg = coord * om;
  float e = (i < 32) ? __sinf(arg) : __cosf(arg);
  float acc = b_in[c] + e;
  acc = __fmaf_rn(c2, w_in[2 * NH + c], acc);
  acc = __fmaf_rn(c1, w_in[1 * NH + c], acc);
  acc = __fmaf_rn(c0, w_in[0 * NH + c], acc);
  return acc;
}

__device__ __forceinline__ float gelu_tanh(float x) {
  float u = 0.7978845608028654f * __fmaf_rn(0.044715f * x, x * x, x);
  float t = 1.0f - 2.0f / (__expf(2.0f * u) + 1.0f);   // tanh(u)
  return 0.5f * x * (1.0f + t);
}

__device__ __forceinline__ void stage_w(uint16_t* wb, const uint16_t* __restrict__ wT, int tid) {
  const uint4* src = (const uint4*)wT;     // 192 rows * 24 chunks of 16B = 4608
  #pragma unroll
  for (int it = 0; it < 18; ++it) {
    int cc = it * 256 + tid;
    int n = cc / 24, p = cc % 24;
    *(uint4*)(wb + n * HROW + p * 8) = src[cc];
  }
}

__device__ __forceinline__ void gemm192(f32x4 acc[8][3], const uint16_t* __restrict__ hb,
                                        const uint16_t* __restrict__ wb, int wave, int lane) {
  const int lrow = lane & 15, lg = lane >> 4;
  #pragma unroll
  for (int kk = 0; kk < 6; ++kk) {
    int koff = kk * 32 + lg * 8;
    s16x8 a[8], bf[3];
    #pragma unroll
    for (int mt = 0; mt < 8; ++mt)
      a[mt] = __builtin_bit_cast(s16x8, *(const uint4*)(hb + (mt * 16 + lrow) * HROW + koff));
    #pragma unroll
    for (int nt = 0; nt < 3; ++nt)
      bf[nt] = __builtin_bit_cast(s16x8, *(const uint4*)(wb + (wave * 48 + nt * 16 + lrow) * HROW + koff));
    #pragma unroll
    for (int mt = 0; mt < 8; ++mt)
      #pragma unroll
      for (int nt = 0; nt < 3; ++nt)
        acc[mt][nt] = __builtin_amdgcn_mfma_f32_16x16x32_bf16(a[mt], bf[nt], acc[mt][nt], 0, 0, 0);
  }
}

__global__ void __launch_bounds__(256) mlp_kernel(
    const float* __restrict__ pts, const int* __restrict__ nbr,
    const float* __restrict__ w_in, const float* __restrict__ b_in,
    const float* __restrict__ b1v, const float* __restrict__ b2v,
    const uint16_t* __restrict__ wT1, const uint16_t* __restrict__ wT2,
    float* __restrict__ out) {
  extern __shared__ char dynsmem[];
  uint16_t* hbuf = (uint16_t*)dynsmem;       // [128][HROW] bf16 (h0, then h1)
  uint16_t* wbuf = hbuf + 128 * HROW;        // [192][HROW] bf16 (wT1, then wT2)
  const int g = blockIdx.x, tid = threadIdx.x;
  const int wave = tid >> 6, lane = tid & 63;

  stage_w(wbuf, wT1, tid);

  { // h0 = nbr@w_in + b_in + sincos  (2 threads per row, 96 cols each, paired b32 writes)
    int r = tid >> 1, half = tid & 1;
    int grow = g * 128 + r;                  // = (b*1024+s)*16 + k
    int b = grow >> 14;
    int pidx = nbr[grow];
    const float* pp = pts + ((size_t)b * NPTS + pidx) * 3;
    float c0 = pp[0], c1 = pp[1], c2 = pp[2];
    for (int jj = 0; jj < 48; ++jj) {
      int c = half * 96 + jj * 2;
      float v0 = h0val(c,     c0, c1, c2, w_in, b_in);
      float v1 = h0val(c + 1, c0, c1, c2, w_in, b_in);
      u32 pk = (u32)f2bf(v0) | ((u32)f2bf(v1) << 16);
      *(u32*)(hbuf + r * HROW + c) = pk;
    }
  }
  __syncthreads();

  f32x4 acc[8][3] = {};
  gemm192(acc, hbuf, wbuf, wave, lane);      // h0 @ w1
  __syncthreads();                            // all reads of hbuf/wbuf done

  { // epilogue 1: +b1, gelu, write h1 (bf16) back into hbuf
    const int lrow = lane & 15, lg = lane >> 4;
    #pragma unroll
    for (int nt = 0; nt < 3; ++nt) {
      int col = wave * 48 + nt * 16 + lrow;
      float bb = b1v[col];
      #pragma unroll
      for (int mt = 0; mt < 8; ++mt) {
        #pragma unroll
        for (int j = 0; j < 4; ++j) {
          int row = mt * 16 + lg * 4 + j;     // verified C/D layout
          hbuf[row * HROW + col] = f2bf(gelu_tanh(acc[mt][nt][j] + bb));
        }
      }
    }
  }
  stage_w(wbuf, wT2, tid);
  __syncthreads();

  f32x4 acc2[8][3] = {};
  gemm192(acc2, hbuf, wbuf, wave, lane);     // h1 @ w2

  { // epilogue 2: mean over the 16 rows of each C-tile (= one supernode) + b2
    const int lrow = lane & 15;
    #pragma unroll
    for (int mt = 0; mt < 8; ++mt) {
      #pragma unroll
      for (int nt = 0; nt < 3; ++nt) {
        float ssum = acc2[mt][nt][0] + acc2[mt][nt][1] + acc2[mt][nt][2] + acc2[mt][nt][3];
        ssum += __shfl_xor(ssum, 16);
        ssum += __shfl_xor(ssum, 32);
        if (lane < 16) {
          int col = wave * 48 + nt * 16 + lrow;
          out[(size_t)(g * 8 + mt) * NH + col] = ssum * 0.0625f + b2v[col];
        }
      }
    }
  }
}

extern "C" void kernel_launch(void* const* d_in, const int* in_sizes, int n_in,
                              void* d_out, int out_size, void* d_ws, size_t ws_size,
                              hipStream_t stream) {
  (void)in_sizes; (void)n_in; (void)out_size; (void)ws_size;
  const float* pts  = (const float*)d_in[0];
  const int*   sidx = (const int*)d_in[1];
  const float* w_in = (const float*)d_in[2];
  const float* b_in = (const float*)d_in[3];
  const float* w1   = (const float*)d_in[4];
  const float* b1   = (const float*)d_in[5];
  const float* w2   = (const float*)d_in[6];
  const float* b2   = (const float*)d_in[7];
  float* out = (float*)d_out;

  int* nbr = (int*)d_ws;                                        // 131072 ints = 512 KB
  uint16_t* wT1 = (uint16_t*)((char*)d_ws + (size_t)NB * NS * NK * 4);
  uint16_t* wT2 = wT1 + NH * NH;                                // +72 KB each

  hipLaunchKernelGGL(prep_weights, dim3(144), dim3(256), 0, stream, w1, w2, wT1, wT2);

  (void)hipFuncSetAttribute((const void*)knn_kernel,
        hipFuncAttributeMaxDynamicSharedMemorySize, NPTS * 3 * 4);
  hipLaunchKernelGGL(knn_kernel, dim3(NB * 32), dim3(256), NPTS * 3 * 4, stream,
                     pts, sidx, nbr);

  const int lds_c = (128 + 192) * HROW * 2;   // 128000 B
  (void)hipFuncSetAttribute((const void*)mlp_kernel,
        hipFuncAttributeMaxDynamicSharedMemorySize, lds_c);
  hipLaunchKernelGGL(mlp_kernel, dim3(NB * NS / 8), dim3(256), lds_c, stream,
                     pts, nbr, w_in, b_in, b1, b2, wT1, wT2, out);
}

// Round 4
// 164.882 us; speedup vs baseline: 2.4457x; 2.4358x over previous
//
#include <hip/hip_runtime.h>
#include <stdint.h>

#define NB   8
#define NPTS 8192
#define NS   1024
#define NK   16
#define NH   192
#define HROW 200   // padded LDS row length in bf16 elems (400 B = 25*16B, stride ≡4 mod 32 dwords)

typedef float    f32x4 __attribute__((ext_vector_type(4)));
typedef short    s16x8 __attribute__((ext_vector_type(8)));
typedef uint32_t u32;
typedef unsigned long long u64;

// round-to-nearest-even f32 -> bf16 (matches numpy/jax RNE; output is internal only)
__device__ __forceinline__ uint16_t f2bf(float f) {
  u32 u = __float_as_uint(f);
  return (uint16_t)((u + 0x7FFFu + ((u >> 16) & 1u)) >> 16);
}

// ---------------- kernel A: transpose + bf16-convert weights (once, tiny) ----------------
__global__ void prep_weights(const float* __restrict__ w1, const float* __restrict__ w2,
                             uint16_t* __restrict__ wT1, uint16_t* __restrict__ wT2) {
  int e = blockIdx.x * 256 + threadIdx.x;
  if (e < NH * NH) {
    int n = e / NH, k = e % NH;
    wT1[n * NH + k] = f2bf(w1[k * NH + n]);
    wT2[n * NH + k] = f2bf(w2[k * NH + n]);
  }
}

// ---------------- kernel B: exact top-16 NN, two-pass threshold scheme ----------------
// v2 post-mortem: the ~180 sequential cross-lane insert events/query were the
// 300us bottleneck (scan cost changed 8x between v1/v2, time didn't move).
// Pass 1: lane-private min over each lane's 128-candidate column (3 VALU/cand,
//   no cross-lane). Bitonic-sort the 64 minima -> sorted top-16 of minima in
//   lanes 0..15; its 16th entry is an upper bound on the true 16th key.
// Pass 2: insert only candidates with key < T that are not the lane's own
//   pass-1 minimum (~2-4 events/query instead of ~180).
// Distances bit-identical to numpy f32 (((dx^2+dy^2)+dz^2), no fma).
// Key = (bits(d)<<32)|idx: u64 order == (dist,idx) lexicographic (exact
// stable-top_k tie semantics; strict < in pass 1 keeps lowest idx on ties).
__global__ void __launch_bounds__(512) knn_kernel(const float* __restrict__ pts,
                                                  const int* __restrict__ sidx,
                                                  int* __restrict__ nbr) {
  extern __shared__ char dynsmem[];
  float* X = (float*)dynsmem;
  float* Y = X + NPTS;
  float* Z = Y + NPTS;
  const int b = blockIdx.x >> 5;       // 32 blocks per sample
  const int chunk = blockIdx.x & 31;
  const float* pb = pts + (size_t)b * NPTS * 3;
  for (int j = threadIdx.x; j < NPTS; j += 512) {
    X[j] = pb[3 * j + 0];
    Y[j] = pb[3 * j + 1];
    Z[j] = pb[3 * j + 2];
  }
  __syncthreads();
  const int wave = threadIdx.x >> 6, lane = threadIdx.x & 63;
  const int sbase = chunk * 32 + wave * 4;   // 4 queries per wave, 8 waves

  float sx[4], sy[4], sz[4], minD[4];
  u32 minI[4];
  #pragma unroll
  for (int q = 0; q < 4; ++q) {
    int si = sidx[b * NS + sbase + q];
    sx[q] = X[si]; sy[q] = Y[si]; sz[q] = Z[si];   // LDS broadcast (uniform addr)
    minD[q] = __uint_as_float(0x7F800000u);
    minI[q] = 0xFFFFFFFFu;
  }

  // ---- pass 1: lane-private minimum of each lane's column (no cross-lane ops)
  for (int t = 0; t < NPTS / 64; ++t) {
    int j = t * 64 + lane;
    float x = X[j], y = Y[j], z = Z[j];
    #pragma unroll
    for (int q = 0; q < 4; ++q) {
      float dx = x - sx[q], dy = y - sy[q], dz = z - sz[q];
      float d = __fadd_rn(__fadd_rn(__fmul_rn(dx, dx), __fmul_rn(dy, dy)),
                          __fmul_rn(dz, dz));
      bool c = d < minD[q];            // strict: keeps lowest idx on exact ties
      minD[q] = c ? d : minD[q];
      minI[q] = c ? (u32)j : minI[q];
    }
  }

  // ---- bitonic sort of the 64 per-lane minima (u64 keys, ascending across lanes)
  u64 arr[4], T[4];
  #pragma unroll
  for (int q = 0; q < 4; ++q) {
    u64 key = ((u64)__float_as_uint(minD[q]) << 32) | minI[q];
    #pragma unroll
    for (int k = 2; k <= 64; k <<= 1) {
      #pragma unroll
      for (int jj = k >> 1; jj > 0; jj >>= 1) {
        u64 p = __shfl_xor(key, jj);
        bool up      = ((lane & k) == 0);
        bool lower   = ((lane & jj) == 0);
        bool takeMin = (lower == up);
        bool pLess   = p < key;
        key = (takeMin == pLess) ? p : key;   // takeMin ? min(key,p) : max(key,p)
      }
    }
    arr[q] = (lane < 16) ? key : ~0ull;       // lanes >=16: +inf sentinel
    T[q] = __shfl(key, 15);                   // upper bound on true 16th key
  }

  // ---- pass 2: exact insertion of the few candidates with key < T
  for (int t = 0; t < NPTS / 64; ++t) {
    int j = t * 64 + lane;
    float x = X[j], y = Y[j], z = Z[j];
    #pragma unroll
    for (int q = 0; q < 4; ++q) {
      float dx = x - sx[q], dy = y - sy[q], dz = z - sz[q];
      float d = __fadd_rn(__fadd_rn(__fmul_rn(dx, dx), __fmul_rn(dy, dy)),
                          __fmul_rn(dz, dz));
      u64 key = ((u64)__float_as_uint(d) << 32) | (u32)j;
      u64 ball = __ballot(key < T[q] && (u32)j != minI[q]);
      if (ball) {                              // wave-uniform, rare
        do {
          int src = __builtin_ctzll(ball);
          ball &= ball - 1;
          u64 k2 = __shfl(key, src);
          if (k2 < T[q]) {                     // recheck: T tightens as we insert
            int r = __popcll(__ballot(arr[q] < k2));   // rank of new key
            u64 up = __shfl_up(arr[q], 1);
            if (lane == r) arr[q] = k2;
            else if (lane > r && lane < 16) arr[q] = up;
            T[q] = __shfl(arr[q], 15);
          }
        } while (ball);
      }
    }
  }
  #pragma unroll
  for (int q = 0; q < 4; ++q)
    if (lane < 16) nbr[(b * NS + sbase + q) * NK + lane] = (int)(u32)arr[q];
}

// ---------------- kernel C: fused gather + sincos embed + MLP (bf16 MFMA) + mean-pool ----
__device__ __forceinline__ float h0val(int c, float c0, float c1, float c2,
                                       const float* __restrict__ w_in,
                                       const float* __restrict__ b_in) {
  int dd = c >> 6;                 // which coordinate (64 channels each)
  int i  = c & 63;                 // [0,32): sin, [32,64): cos
  float coord = (dd == 0) ? c0 : ((dd == 1) ? c1 : c2);
  float om = exp2f((float)(i & 31) * -0.41524101186092029f);
  float arg = coord * om;
  float e = (i < 32) ? __sinf(arg) : __cosf(arg);
  float acc = b_in[c] + e;
  acc = __fmaf_rn(c2, w_in[2 * NH + c], acc);
  acc = __fmaf_rn(c1, w_in[1 * NH + c], acc);
  acc = __fmaf_rn(c0, w_in[0 * NH + c], acc);
  return acc;
}

__device__ __forceinline__ float gelu_tanh(float x) {
  float u = 0.7978845608028654f * __fmaf_rn(0.044715f * x, x * x, x);
  float t = 1.0f - 2.0f / (__expf(2.0f * u) + 1.0f);   // tanh(u)
  return 0.5f * x * (1.0f + t);
}

__device__ __forceinline__ void stage_w(uint16_t* wb, const uint16_t* __restrict__ wT, int tid) {
  const uint4* src = (const uint4*)wT;     // 192 rows * 24 chunks of 16B = 4608
  #pragma unroll
  for (int it = 0; it < 18; ++it) {
    int cc = it * 256 + tid;
    int n = cc / 24, p = cc % 24;
    *(uint4*)(wb + n * HROW + p * 8) = src[cc];
  }
}

__device__ __forceinline__ void gemm192(f32x4 acc[8][3], const uint16_t* __restrict__ hb,
                                        const uint16_t* __restrict__ wb, int wave, int lane) {
  const int lrow = lane & 15, lg = lane >> 4;
  #pragma unroll
  for (int kk = 0; kk < 6; ++kk) {
    int koff = kk * 32 + lg * 8;
    s16x8 a[8], bf[3];
    #pragma unroll
    for (int mt = 0; mt < 8; ++mt)
      a[mt] = __builtin_bit_cast(s16x8, *(const uint4*)(hb + (mt * 16 + lrow) * HROW + koff));
    #pragma unroll
    for (int nt = 0; nt < 3; ++nt)
      bf[nt] = __builtin_bit_cast(s16x8, *(const uint4*)(wb + (wave * 48 + nt * 16 + lrow) * HROW + koff));
    #pragma unroll
    for (int mt = 0; mt < 8; ++mt)
      #pragma unroll
      for (int nt = 0; nt < 3; ++nt)
        acc[mt][nt] = __builtin_amdgcn_mfma_f32_16x16x32_bf16(a[mt], bf[nt], acc[mt][nt], 0, 0, 0);
  }
}

__global__ void __launch_bounds__(256) mlp_kernel(
    const float* __restrict__ pts, const int* __restrict__ nbr,
    const float* __restrict__ w_in, const float* __restrict__ b_in,
    const float* __restrict__ b1v, const float* __restrict__ b2v,
    const uint16_t* __restrict__ wT1, const uint16_t* __restrict__ wT2,
    float* __restrict__ out) {
  extern __shared__ char dynsmem[];
  uint16_t* hbuf = (uint16_t*)dynsmem;       // [128][HROW] bf16 (h0, then h1)
  uint16_t* wbuf = hbuf + 128 * HROW;        // [192][HROW] bf16 (wT1, then wT2)
  const int g = blockIdx.x, tid = threadIdx.x;
  const int wave = tid >> 6, lane = tid & 63;

  stage_w(wbuf, wT1, tid);

  { // h0 = nbr@w_in + b_in + sincos  (2 threads per row, 96 cols each, paired b32 writes)
    int r = tid >> 1, half = tid & 1;
    int grow = g * 128 + r;                  // = (b*1024+s)*16 + k
    int b = grow >> 14;
    int pidx = nbr[grow];
    const float* pp = pts + ((size_t)b * NPTS + pidx) * 3;
    float c0 = pp[0], c1 = pp[1], c2 = pp[2];
    for (int jj = 0; jj < 48; ++jj) {
      int c = half * 96 + jj * 2;
      float v0 = h0val(c,     c0, c1, c2, w_in, b_in);
      float v1 = h0val(c + 1, c0, c1, c2, w_in, b_in);
      u32 pk = (u32)f2bf(v0) | ((u32)f2bf(v1) << 16);
      *(u32*)(hbuf + r * HROW + c) = pk;
    }
  }
  __syncthreads();

  f32x4 acc[8][3] = {};
  gemm192(acc, hbuf, wbuf, wave, lane);      // h0 @ w1
  __syncthreads();                            // all reads of hbuf/wbuf done

  { // epilogue 1: +b1, gelu, write h1 (bf16) back into hbuf
    const int lrow = lane & 15, lg = lane >> 4;
    #pragma unroll
    for (int nt = 0; nt < 3; ++nt) {
      int col = wave * 48 + nt * 16 + lrow;
      float bb = b1v[col];
      #pragma unroll
      for (int mt = 0; mt < 8; ++mt) {
        #pragma unroll
        for (int j = 0; j < 4; ++j) {
          int row = mt * 16 + lg * 4 + j;     // verified C/D layout
          hbuf[row * HROW + col] = f2bf(gelu_tanh(acc[mt][nt][j] + bb));
        }
      }
    }
  }
  stage_w(wbuf, wT2, tid);
  __syncthreads();

  f32x4 acc2[8][3] = {};
  gemm192(acc2, hbuf, wbuf, wave, lane);     // h1 @ w2

  { // epilogue 2: mean over the 16 rows of each C-tile (= one supernode) + b2
    const int lrow = lane & 15;
    #pragma unroll
    for (int mt = 0; mt < 8; ++mt) {
      #pragma unroll
      for (int nt = 0; nt < 3; ++nt) {
        float ssum = acc2[mt][nt][0] + acc2[mt][nt][1] + acc2[mt][nt][2] + acc2[mt][nt][3];
        ssum += __shfl_xor(ssum, 16);
        ssum += __shfl_xor(ssum, 32);
        if (lane < 16) {
          int col = wave * 48 + nt * 16 + lrow;
          out[(size_t)(g * 8 + mt) * NH + col] = ssum * 0.0625f + b2v[col];
        }
      }
    }
  }
}

extern "C" void kernel_launch(void* const* d_in, const int* in_sizes, int n_in,
                              void* d_out, int out_size, void* d_ws, size_t ws_size,
                              hipStream_t stream) {
  (void)in_sizes; (void)n_in; (void)out_size; (void)ws_size;
  const float* pts  = (const float*)d_in[0];
  const int*   sidx = (const int*)d_in[1];
  const float* w_in = (const float*)d_in[2];
  const float* b_in = (const float*)d_in[3];
  const float* w1   = (const float*)d_in[4];
  const float* b1   = (const float*)d_in[5];
  const float* w2   = (const float*)d_in[6];
  const float* b2   = (const float*)d_in[7];
  float* out = (float*)d_out;

  int* nbr = (int*)d_ws;                                        // 131072 ints = 512 KB
  uint16_t* wT1 = (uint16_t*)((char*)d_ws + (size_t)NB * NS * NK * 4);
  uint16_t* wT2 = wT1 + NH * NH;                                // +72 KB each

  hipLaunchKernelGGL(prep_weights, dim3(144), dim3(256), 0, stream, w1, w2, wT1, wT2);

  (void)hipFuncSetAttribute((const void*)knn_kernel,
        hipFuncAttributeMaxDynamicSharedMemorySize, NPTS * 3 * 4);
  hipLaunchKernelGGL(knn_kernel, dim3(NB * 32), dim3(512), NPTS * 3 * 4, stream,
                     pts, sidx, nbr);

  const int lds_c = (128 + 192) * HROW * 2;   // 128000 B
  (void)hipFuncSetAttribute((const void*)mlp_kernel,
        hipFuncAttributeMaxDynamicSharedMemorySize, lds_c);
  hipLaunchKernelGGL(mlp_kernel, dim3(NB * NS / 8), dim3(256), lds_c, stream,
                     pts, nbr, w_in, b_in, b1, b2, wT1, wT2, out);
}

// Round 5
// 114.149 us; speedup vs baseline: 3.5326x; 1.4444x over previous
//
#include <hip/hip_runtime.h>
#include <stdint.h>

#define NB   8
#define NPTS 8192
#define NS   1024
#define NK   16
#define NH   192
#define KP1  224   // extended K for gemm1: 192 embed + 3 coords + 1 bias + 28 zero pad
#define HROW 232   // LDS row stride (464 B, 16B-aligned; 116 dw = 20 mod 32 -> 2-way max)

typedef float    f32x4 __attribute__((ext_vector_type(4)));
typedef short    s16x8 __attribute__((ext_vector_type(8)));
typedef uint32_t u32;
typedef unsigned long long u64;

// omega_m = 10000^(-m/32) = 10^(-m/8), exact table (compile-time folds)
static __device__ const float OMEGA[32] = {
  1.0f, 0.74989420933245585f, 0.56234132519034907f, 0.42169650342858223f,
  0.31622776601683794f, 0.23713737056616552f, 0.17782794100389229f, 0.13335214321633237f,
  0.1f, 0.074989420933245585f, 0.056234132519034907f, 0.042169650342858223f,
  0.031622776601683794f, 0.023713737056616552f, 0.017782794100389229f, 0.013335214321633237f,
  0.01f, 0.0074989420933245585f, 0.0056234132519034907f, 0.0042169650342858223f,
  0.0031622776601683794f, 0.0023713737056616552f, 0.0017782794100389229f, 0.0013335214321633237f,
  0.001f, 0.00074989420933245585f, 0.00056234132519034907f, 0.00042169650342858223f,
  0.00031622776601683794f, 0.00023713737056616552f, 0.00017782794100389229f, 0.00013335214321633237f };

// round-to-nearest-even f32 -> bf16
__device__ __forceinline__ uint16_t f2bf(float f) {
  u32 u = __float_as_uint(f);
  return (uint16_t)((u + 0x7FFFu + ((u >> 16) & 1u)) >> 16);
}

// ---------------- kernel A: build extended transposed weights ----------------
// wT1e[n][0..191]  = bf16(w1[k][n])           (transpose)
// wT1e[n][192+d]   = bf16(sum_c w_in[d][c]*w1[c][n])   (folded input projection)
// wT1e[n][195]     = bf16(sum_c b_in[c]*w1[c][n] + b1[n])  (folded biases)
// wT1e[n][196..223]= 0
// wT2[n][0..191]   = bf16(w2[k][n])
__global__ void __launch_bounds__(64) prep_weights(
    const float* __restrict__ w_in, const float* __restrict__ b_in,
    const float* __restrict__ w1, const float* __restrict__ b1,
    const float* __restrict__ w2,
    uint16_t* __restrict__ wT1e, uint16_t* __restrict__ wT2) {
  const int n = blockIdx.x, t = threadIdx.x;
  float p0 = 0, p1 = 0, p2 = 0, pb = 0;
  #pragma unroll
  for (int kk = 0; kk < 3; ++kk) {
    int c = kk * 64 + t;
    float w1cn = w1[c * NH + n];
    wT1e[n * KP1 + c] = f2bf(w1cn);
    wT2 [n * NH  + c] = f2bf(w2[c * NH + n]);
    p0 = fmaf(w_in[0 * NH + c], w1cn, p0);
    p1 = fmaf(w_in[1 * NH + c], w1cn, p1);
    p2 = fmaf(w_in[2 * NH + c], w1cn, p2);
    pb = fmaf(b_in[c], w1cn, pb);
  }
  #pragma unroll
  for (int off = 32; off; off >>= 1) {
    p0 += __shfl_down(p0, off);
    p1 += __shfl_down(p1, off);
    p2 += __shfl_down(p2, off);
    pb += __shfl_down(pb, off);
  }
  if (t == 0) {
    wT1e[n * KP1 + 192] = f2bf(p0);
    wT1e[n * KP1 + 193] = f2bf(p1);
    wT1e[n * KP1 + 194] = f2bf(p2);
    wT1e[n * KP1 + 195] = f2bf(pb + b1[n]);
  }
  if (t >= 4 && t < 32) wT1e[n * KP1 + 192 + t] = 0;
}

// ---------------- kernel B: exact top-16 NN, two-pass threshold scheme (unchanged) ----
__global__ void __launch_bounds__(512) knn_kernel(const float* __restrict__ pts,
                                                  const int* __restrict__ sidx,
                                                  int* __restrict__ nbr) {
  extern __shared__ char dynsmem[];
  float* X = (float*)dynsmem;
  float* Y = X + NPTS;
  float* Z = Y + NPTS;
  const int b = blockIdx.x >> 5;
  const int chunk = blockIdx.x & 31;
  const float* pb = pts + (size_t)b * NPTS * 3;
  for (int j = threadIdx.x; j < NPTS; j += 512) {
    X[j] = pb[3 * j + 0];
    Y[j] = pb[3 * j + 1];
    Z[j] = pb[3 * j + 2];
  }
  __syncthreads();
  const int wave = threadIdx.x >> 6, lane = threadIdx.x & 63;
  const int sbase = chunk * 32 + wave * 4;

  float sx[4], sy[4], sz[4], minD[4];
  u32 minI[4];
  #pragma unroll
  for (int q = 0; q < 4; ++q) {
    int si = sidx[b * NS + sbase + q];
    sx[q] = X[si]; sy[q] = Y[si]; sz[q] = Z[si];
    minD[q] = __uint_as_float(0x7F800000u);
    minI[q] = 0xFFFFFFFFu;
  }

  for (int t = 0; t < NPTS / 64; ++t) {
    int j = t * 64 + lane;
    float x = X[j], y = Y[j], z = Z[j];
    #pragma unroll
    for (int q = 0; q < 4; ++q) {
      float dx = x - sx[q], dy = y - sy[q], dz = z - sz[q];
      float d = __fadd_rn(__fadd_rn(__fmul_rn(dx, dx), __fmul_rn(dy, dy)),
                          __fmul_rn(dz, dz));
      bool c = d < minD[q];
      minD[q] = c ? d : minD[q];
      minI[q] = c ? (u32)j : minI[q];
    }
  }

  u64 arr[4], T[4];
  #pragma unroll
  for (int q = 0; q < 4; ++q) {
    u64 key = ((u64)__float_as_uint(minD[q]) << 32) | minI[q];
    #pragma unroll
    for (int k = 2; k <= 64; k <<= 1) {
      #pragma unroll
      for (int jj = k >> 1; jj > 0; jj >>= 1) {
        u64 p = __shfl_xor(key, jj);
        bool up      = ((lane & k) == 0);
        bool lower   = ((lane & jj) == 0);
        bool takeMin = (lower == up);
        bool pLess   = p < key;
        key = (takeMin == pLess) ? p : key;
      }
    }
    arr[q] = (lane < 16) ? key : ~0ull;
    T[q] = __shfl(key, 15);
  }

  for (int t = 0; t < NPTS / 64; ++t) {
    int j = t * 64 + lane;
    float x = X[j], y = Y[j], z = Z[j];
    #pragma unroll
    for (int q = 0; q < 4; ++q) {
      float dx = x - sx[q], dy = y - sy[q], dz = z - sz[q];
      float d = __fadd_rn(__fadd_rn(__fmul_rn(dx, dx), __fmul_rn(dy, dy)),
                          __fmul_rn(dz, dz));
      u64 key = ((u64)__float_as_uint(d) << 32) | (u32)j;
      u64 ball = __ballot(key < T[q] && (u32)j != minI[q]);
      if (ball) {
        do {
          int src = __builtin_ctzll(ball);
          ball &= ball - 1;
          u64 k2 = __shfl(key, src);
          if (k2 < T[q]) {
            int r = __popcll(__ballot(arr[q] < k2));
            u64 up = __shfl_up(arr[q], 1);
            if (lane == r) arr[q] = k2;
            else if (lane > r && lane < 16) arr[q] = up;
            T[q] = __shfl(arr[q], 15);
          }
        } while (ball);
      }
    }
  }
  #pragma unroll
  for (int q = 0; q < 4; ++q)
    if (lane < 16) nbr[(b * NS + sbase + q) * NK + lane] = (int)(u32)arr[q];
}

// ---------------- kernel C: gather + embed + MLP (B-fragments from L2, LDS=hbuf only) ----
__device__ __forceinline__ float h0ch(int c, const float crd[3]) {
  if (c >= 196) return 0.0f;          // zero pad (compile-time resolved: loop unrolled)
  if (c == 195) return 1.0f;          // bias channel
  if (c >= 192) return crd[c - 192];  // folded input-projection channels
  int dd = c >> 6, i = c & 63, m = i & 31;
  float arg = crd[dd] * OMEGA[m];
  return (i < 32) ? __sinf(arg) : __cosf(arg);
}

__device__ __forceinline__ float gelu_tanh(float x) {
  float u = 0.7978845608028654f * __fmaf_rn(0.044715f * x, x * x, x);
  float t = 1.0f - 2.0f / (__expf(2.0f * u) + 1.0f);   // tanh(u)
  return 0.5f * x * (1.0f + t);
}

template<int NKK, int WS>
__device__ __forceinline__ void gemmG(f32x4 acc[8][3], const uint16_t* hb,
                                      const uint16_t* __restrict__ wT,
                                      int wave, int lane) {
  const int lrow = lane & 15, lg = lane >> 4;
  const uint16_t* wb = wT + (size_t)(wave * 48 + lrow) * WS + lg * 8;
  #pragma unroll
  for (int kk = 0; kk < NKK; ++kk) {
    const int koff = kk * 32;
    s16x8 bf[3];
    #pragma unroll
    for (int nt = 0; nt < 3; ++nt)
      bf[nt] = __builtin_bit_cast(s16x8, *(const uint4*)(wb + nt * 16 * WS + koff));
    s16x8 a[8];
    #pragma unroll
    for (int mt = 0; mt < 8; ++mt)
      a[mt] = __builtin_bit_cast(s16x8, *(const uint4*)(hb + (mt * 16 + lrow) * HROW + koff + lg * 8));
    #pragma unroll
    for (int mt = 0; mt < 8; ++mt)
      #pragma unroll
      for (int nt = 0; nt < 3; ++nt)
        acc[mt][nt] = __builtin_amdgcn_mfma_f32_16x16x32_bf16(a[mt], bf[nt], acc[mt][nt], 0, 0, 0);
  }
}

__global__ void __launch_bounds__(256) mlp_kernel(
    const float* __restrict__ pts, const int* __restrict__ nbr,
    const float* __restrict__ b2v,
    const uint16_t* __restrict__ wT1e, const uint16_t* __restrict__ wT2,
    float* __restrict__ out) {
  __shared__ uint16_t hbuf[128 * HROW];   // 59.4 KB -> 2 blocks/CU
  const int g = blockIdx.x, tid = threadIdx.x;
  const int wave = tid >> 6, lane = tid & 63;

  { // h0 fill: [sincos embed | coords | 1 | zeros], 2 threads/row, 56 col-pairs each
    int r = tid >> 1, half = tid & 1;
    int grow = g * 128 + r;                  // = (b*1024+s)*16 + k
    int b = grow >> 14;
    int pidx = nbr[grow];
    const float* pp = pts + ((size_t)b * NPTS + pidx) * 3;
    float crd[3] = {pp[0], pp[1], pp[2]};
    #pragma unroll
    for (int jj = 0; jj < 56; ++jj) {
      int c = half * 112 + jj * 2;
      u32 pk = (u32)f2bf(h0ch(c, crd)) | ((u32)f2bf(h0ch(c + 1, crd)) << 16);
      *(u32*)(hbuf + r * HROW + c) = pk;
    }
  }
  __syncthreads();

  f32x4 acc[8][3] = {};
  gemmG<7, KP1>(acc, hbuf, wT1e, wave, lane);   // (E|coords|1) @ w1e  == h0@w1 + b1
  __syncthreads();                               // all gemm1 reads done before overwrite

  { // epilogue 1: gelu (b1 already folded), write h1 back into hbuf cols 0..191
    const int lrow = lane & 15, lg = lane >> 4;
    #pragma unroll
    for (int nt = 0; nt < 3; ++nt) {
      int col = wave * 48 + nt * 16 + lrow;
      #pragma unroll
      for (int mt = 0; mt < 8; ++mt) {
        #pragma unroll
        for (int j = 0; j < 4; ++j) {
          int row = mt * 16 + lg * 4 + j;       // verified C/D layout
          hbuf[row * HROW + col] = f2bf(gelu_tanh(acc[mt][nt][j]));
        }
      }
    }
  }
  __syncthreads();

  f32x4 acc2[8][3] = {};
  gemmG<6, NH>(acc2, hbuf, wT2, wave, lane);    // h1 @ w2

  { // epilogue 2: mean over 16 rows of each C-tile (one supernode) + b2
    const int lrow = lane & 15;
    #pragma unroll
    for (int mt = 0; mt < 8; ++mt) {
      #pragma unroll
      for (int nt = 0; nt < 3; ++nt) {
        float ssum = acc2[mt][nt][0] + acc2[mt][nt][1] + acc2[mt][nt][2] + acc2[mt][nt][3];
        ssum += __shfl_xor(ssum, 16);
        ssum += __shfl_xor(ssum, 32);
        if (lane < 16) {
          int col = wave * 48 + nt * 16 + lrow;
          out[(size_t)(g * 8 + mt) * NH + col] = ssum * 0.0625f + b2v[col];
        }
      }
    }
  }
}

extern "C" void kernel_launch(void* const* d_in, const int* in_sizes, int n_in,
                              void* d_out, int out_size, void* d_ws, size_t ws_size,
                              hipStream_t stream) {
  (void)in_sizes; (void)n_in; (void)out_size; (void)ws_size;
  const float* pts  = (const float*)d_in[0];
  const int*   sidx = (const int*)d_in[1];
  const float* w_in = (const float*)d_in[2];
  const float* b_in = (const float*)d_in[3];
  const float* w1   = (const float*)d_in[4];
  const float* b1   = (const float*)d_in[5];
  const float* w2   = (const float*)d_in[6];
  const float* b2   = (const float*)d_in[7];
  float* out = (float*)d_out;

  int* nbr = (int*)d_ws;                                        // 131072 ints = 512 KB
  uint16_t* wT1e = (uint16_t*)((char*)d_ws + (size_t)NB * NS * NK * 4);
  uint16_t* wT2  = wT1e + NH * KP1;                             // +84 KB, +72 KB

  hipLaunchKernelGGL(prep_weights, dim3(NH), dim3(64), 0, stream,
                     w_in, b_in, w1, b1, w2, wT1e, wT2);

  (void)hipFuncSetAttribute((const void*)knn_kernel,
        hipFuncAttributeMaxDynamicSharedMemorySize, NPTS * 3 * 4);
  hipLaunchKernelGGL(knn_kernel, dim3(NB * 32), dim3(512), NPTS * 3 * 4, stream,
                     pts, sidx, nbr);

  hipLaunchKernelGGL(mlp_kernel, dim3(NB * NS / 8), dim3(256), 0, stream,
                     pts, nbr, b2, wT1e, wT2, out);
}

// Round 6
// 108.474 us; speedup vs baseline: 3.7175x; 1.0523x over previous
//
#include <hip/hip_runtime.h>
#include <stdint.h>

#define NB   8
#define NPTS 8192
#define NS   1024
#define NK   16
#define NH   192
#define KP1  224   // extended K for gemm1: 192 embed + 3 coords + 1 bias + 28 zero pad
#define HROW 232   // LDS row stride in bf16 elems
#define HALF 4096  // points per knn half-block

typedef float    f32x4 __attribute__((ext_vector_type(4)));
typedef short    s16x8 __attribute__((ext_vector_type(8)));
typedef uint32_t u32;
typedef unsigned long long u64;

// omega_m = 10000^(-m/32) = 10^(-m/8), exact table
static __device__ const float OMEGA[32] = {
  1.0f, 0.74989420933245585f, 0.56234132519034907f, 0.42169650342858223f,
  0.31622776601683794f, 0.23713737056616552f, 0.17782794100389229f, 0.13335214321633237f,
  0.1f, 0.074989420933245585f, 0.056234132519034907f, 0.042169650342858223f,
  0.031622776601683794f, 0.023713737056616552f, 0.017782794100389229f, 0.013335214321633237f,
  0.01f, 0.0074989420933245585f, 0.0056234132519034907f, 0.0042169650342858223f,
  0.0031622776601683794f, 0.0023713737056616552f, 0.0017782794100389229f, 0.0013335214321633237f,
  0.001f, 0.00074989420933245585f, 0.00056234132519034907f, 0.00042169650342858223f,
  0.00031622776601683794f, 0.00023713737056616552f, 0.00017782794100389229f, 0.00013335214321633237f };

__device__ __forceinline__ uint16_t f2bf(float f) {
  u32 u = __float_as_uint(f);
  return (uint16_t)((u + 0x7FFFu + ((u >> 16) & 1u)) >> 16);
}

// ---------------- kernel A: build extended transposed weights ----------------
__global__ void __launch_bounds__(64) prep_weights(
    const float* __restrict__ w_in, const float* __restrict__ b_in,
    const float* __restrict__ w1, const float* __restrict__ b1,
    const float* __restrict__ w2,
    uint16_t* __restrict__ wT1e, uint16_t* __restrict__ wT2) {
  const int n = blockIdx.x, t = threadIdx.x;
  float p0 = 0, p1 = 0, p2 = 0, pb = 0;
  #pragma unroll
  for (int kk = 0; kk < 3; ++kk) {
    int c = kk * 64 + t;
    float w1cn = w1[c * NH + n];
    wT1e[n * KP1 + c] = f2bf(w1cn);
    wT2 [n * NH  + c] = f2bf(w2[c * NH + n]);
    p0 = fmaf(w_in[0 * NH + c], w1cn, p0);
    p1 = fmaf(w_in[1 * NH + c], w1cn, p1);
    p2 = fmaf(w_in[2 * NH + c], w1cn, p2);
    pb = fmaf(b_in[c], w1cn, pb);
  }
  #pragma unroll
  for (int off = 32; off; off >>= 1) {
    p0 += __shfl_down(p0, off);
    p1 += __shfl_down(p1, off);
    p2 += __shfl_down(p2, off);
    pb += __shfl_down(pb, off);
  }
  if (t == 0) {
    wT1e[n * KP1 + 192] = f2bf(p0);
    wT1e[n * KP1 + 193] = f2bf(p1);
    wT1e[n * KP1 + 194] = f2bf(p2);
    wT1e[n * KP1 + 195] = f2bf(pb + b1[n]);
  }
  if (t >= 4 && t < 32) wT1e[n * KP1 + 192 + t] = 0;
}

// ---------------- kernel B: exact top-16 over a HALF of the points ----------------
// Split-by-points: block = (sample b, 32-query chunk, half) scans 4096 points
// (48KB LDS -> 2 blocks/CU -> 4 waves/SIMD, vs 96KB/1 block/2 waves before).
// Emits the exact SORTED top-16 u64 keys of its half; mlp prologue merges.
// Key = (bits(d)<<32) | global_idx: u64 order == (dist, idx) lexicographic ->
// exact stable-top_k tie semantics, merge-invariant across halves.
// Distances bit-identical to numpy f32 (((dx^2+dy^2)+dz^2), no fma).
__global__ void __launch_bounds__(512) knn_kernel(const float* __restrict__ pts,
                                                  const int* __restrict__ sidx,
                                                  u64* __restrict__ keys) {
  __shared__ float2 XY[HALF];   // 32 KB
  __shared__ float  Zs[HALF];   // 16 KB
  const int bid = blockIdx.x;
  const int b = bid >> 6;
  const int chunk = (bid >> 1) & 31;
  const int half = bid & 1;
  const int pbase = half * HALF;
  const float* pb = pts + ((size_t)b * NPTS + pbase) * 3;
  for (int i = threadIdx.x; i < HALF; i += 512) {
    XY[i] = float2{pb[3 * i], pb[3 * i + 1]};
    Zs[i] = pb[3 * i + 2];
  }
  __syncthreads();
  const int wave = threadIdx.x >> 6, lane = threadIdx.x & 63;
  const int sbase = chunk * 32 + wave * 4;

  float sx[4], sy[4], sz[4], minD[4], Td[4];
  u32 minI[4];
  u64 arr[4], T[4];
  #pragma unroll
  for (int q = 0; q < 4; ++q) {
    int si = sidx[b * NS + sbase + q];
    const float* qp = pts + ((size_t)b * NPTS + si) * 3;   // L2 broadcast
    sx[q] = qp[0]; sy[q] = qp[1]; sz[q] = qp[2];
    minD[q] = __uint_as_float(0x7F800000u);
    minI[q] = 0xFFFFFFFFu;
  }

  // ---- pass 1: lane-private minimum of each lane's 64-candidate column
  for (int t = 0; t < HALF / 64; ++t) {
    int lj = t * 64 + lane;
    float2 xy = XY[lj];
    float z = Zs[lj];
    #pragma unroll
    for (int q = 0; q < 4; ++q) {
      float dx = xy.x - sx[q], dy = xy.y - sy[q], dz = z - sz[q];
      float d = __fadd_rn(__fadd_rn(__fmul_rn(dx, dx), __fmul_rn(dy, dy)),
                          __fmul_rn(dz, dz));
      bool c = d < minD[q];            // strict: keeps lowest idx on exact ties
      minD[q] = c ? d : minD[q];
      minI[q] = c ? (u32)(pbase + lj) : minI[q];
    }
  }

  // ---- bitonic sort of the 64 per-lane minima (ascending across lanes)
  #pragma unroll
  for (int q = 0; q < 4; ++q) {
    u64 key = ((u64)__float_as_uint(minD[q]) << 32) | minI[q];
    #pragma unroll
    for (int k = 2; k <= 64; k <<= 1) {
      #pragma unroll
      for (int jj = k >> 1; jj > 0; jj >>= 1) {
        u64 p = __shfl_xor(key, jj);
        bool up      = ((lane & k) == 0);
        bool lower   = ((lane & jj) == 0);
        bool takeMin = (lower == up);
        bool pLess   = p < key;
        key = (takeMin == pLess) ? p : key;
      }
    }
    arr[q] = (lane < 16) ? key : ~0ull;
    T[q] = __shfl(key, 15);                       // upper bound on true 16th key
    Td[q] = __uint_as_float((u32)(T[q] >> 32));
  }

  // ---- pass 2: exact insertion of the few candidates below the threshold
  for (int t = 0; t < HALF / 64; ++t) {
    int lj = t * 64 + lane;
    float2 xy = XY[lj];
    float z = Zs[lj];
    #pragma unroll
    for (int q = 0; q < 4; ++q) {
      float dx = xy.x - sx[q], dy = xy.y - sy[q], dz = z - sz[q];
      float d = __fadd_rn(__fadd_rn(__fmul_rn(dx, dx), __fmul_rn(dy, dy)),
                          __fmul_rn(dz, dz));
      // float-threshold superset test (d<=Td covers key<T incl. dist ties);
      // own pass-1 minimum excluded (it is either already in arr or > T).
      u64 ball = __ballot(d <= Td[q] && (u32)(pbase + lj) != minI[q]);
      if (ball) {                                 // wave-uniform, rare
        u64 key = ((u64)__float_as_uint(d) << 32) | (u32)(pbase + lj);
        do {
          int src = __builtin_ctzll(ball);
          ball &= ball - 1;
          u64 k2 = __shfl(key, src);
          if (k2 < T[q]) {                        // exact (dist,idx) compare
            int r = __popcll(__ballot(arr[q] < k2));
            u64 up = __shfl_up(arr[q], 1);
            if (lane == r) arr[q] = k2;
            else if (lane > r && lane < 16) arr[q] = up;
            T[q] = __shfl(arr[q], 15);
            Td[q] = __uint_as_float((u32)(T[q] >> 32));
          }
        } while (ball);
      }
    }
  }
  #pragma unroll
  for (int q = 0; q < 4; ++q)
    if (lane < 16)
      keys[((size_t)(b * NS + sbase + q)) * 32 + half * 16 + lane] = arr[q];
}

// ---------------- kernel C: merge + gather + embed + MLP + mean-pool ----------------
__device__ __forceinline__ float h0ch(int c, const float crd[3]) {
  if (c >= 196) return 0.0f;
  if (c == 195) return 1.0f;          // bias channel
  if (c >= 192) return crd[c - 192];  // folded input-projection channels
  int dd = c >> 6, i = c & 63, m = i & 31;
  float arg = crd[dd] * OMEGA[m];
  return (i < 32) ? __sinf(arg) : __cosf(arg);
}

__device__ __forceinline__ float gelu_tanh(float x) {
  float u = 0.7978845608028654f * __fmaf_rn(0.044715f * x, x * x, x);
  float t = 1.0f - 2.0f / (__expf(2.0f * u) + 1.0f);   // tanh(u)
  return 0.5f * x * (1.0f + t);
}

__global__ void __launch_bounds__(256) mlp_kernel(
    const float* __restrict__ pts, const u64* __restrict__ keys,
    const float* __restrict__ b2v,
    const uint16_t* __restrict__ wT1e, const uint16_t* __restrict__ wT2,
    float* __restrict__ out) {
  __shared__ uint16_t hbuf[128 * HROW];   // 59.4 KB -> 2 blocks/CU
  __shared__ int nbrL[128];
  const int g = blockIdx.x, tid = threadIdx.x;
  const int wave = tid >> 6, lane = tid & 63;
  const int lrow = lane & 15, lg = lane >> 4;

  { // merge the two sorted 16-lists per query (rank of each key among the 32)
    int qq = tid >> 5;                   // query within block (0..7)
    u64 k0 = keys[((size_t)g * 8 + qq) * 32 + (tid & 31)];
    int rank = 0;
    #pragma unroll
    for (int p = 0; p < 32; ++p) {
      u64 other = __shfl(k0, (lane & 32) + p);
      rank += (other < k0);              // keys globally unique
    }
    if (rank < 16) nbrL[qq * 16 + rank] = (int)(u32)k0;
  }
  __syncthreads();

  { // h0 fill: [sincos embed | coords | 1 | zeros], 2 threads per row
    int r = tid >> 1, half = tid & 1;
    int grow = g * 128 + r;
    int b = grow >> 14;
    int pidx = nbrL[r];
    const float* pp = pts + ((size_t)b * NPTS + pidx) * 3;
    float crd[3] = {pp[0], pp[1], pp[2]};
    #pragma unroll
    for (int jj = 0; jj < 56; ++jj) {
      int c = half * 112 + jj * 2;
      u32 pk = (u32)f2bf(h0ch(c, crd)) | ((u32)f2bf(h0ch(c + 1, crd)) << 16);
      *(u32*)(hbuf + r * HROW + c) = pk;
    }
  }
  __syncthreads();

  // ---- gemm1 (SWAPPED operands): D1^T = wT1e-as-A x h0-as-B.
  // D col (lane&15) = m-row, D row = n -> gelu writes become contiguous b64.
  f32x4 acc1[3][8] = {};
  {
    const uint16_t* wbase = wT1e + (size_t)(wave * 48 + lrow) * KP1 + lg * 8;
    uint4 anx[3];
    #pragma unroll
    for (int nt = 0; nt < 3; ++nt) anx[nt] = *(const uint4*)(wbase + nt * 16 * KP1);
    #pragma unroll
    for (int kk = 0; kk < 7; ++kk) {
      uint4 acur[3];
      #pragma unroll
      for (int nt = 0; nt < 3; ++nt) acur[nt] = anx[nt];
      if (kk < 6) {
        #pragma unroll
        for (int nt = 0; nt < 3; ++nt)
          anx[nt] = *(const uint4*)(wbase + nt * 16 * KP1 + (kk + 1) * 32);
      }
      s16x8 bm[8];
      #pragma unroll
      for (int mt = 0; mt < 8; ++mt)
        bm[mt] = __builtin_bit_cast(s16x8,
                   *(const uint4*)(hbuf + (mt * 16 + lrow) * HROW + kk * 32 + lg * 8));
      #pragma unroll
      for (int nt = 0; nt < 3; ++nt)
        #pragma unroll
        for (int mt = 0; mt < 8; ++mt)
          acc1[nt][mt] = __builtin_amdgcn_mfma_f32_16x16x32_bf16(
              __builtin_bit_cast(s16x8, acur[nt]), bm[mt], acc1[nt][mt], 0, 0, 0);
    }
  }
  __syncthreads();   // all gemm1 reads of hbuf done before h1 overwrite

  { // epilogue 1: gelu (b1 folded), write h1: 4 consecutive cols per b64 write
    #pragma unroll
    for (int nt = 0; nt < 3; ++nt) {
      #pragma unroll
      for (int mt = 0; mt < 8; ++mt) {
        u32 lo = (u32)f2bf(gelu_tanh(acc1[nt][mt][0])) |
                 ((u32)f2bf(gelu_tanh(acc1[nt][mt][1])) << 16);
        u32 hi = (u32)f2bf(gelu_tanh(acc1[nt][mt][2])) |
                 ((u32)f2bf(gelu_tanh(acc1[nt][mt][3])) << 16);
        *(uint2*)(hbuf + (mt * 16 + lrow) * HROW + wave * 48 + nt * 16 + lg * 4) =
            uint2{lo, hi};
      }
    }
  }
  __syncthreads();

  // ---- gemm2 (normal orientation): D2 = h1-as-A x wT2-as-B
  f32x4 acc2[8][3] = {};
  {
    const uint16_t* w2base = wT2 + (size_t)(wave * 48 + lrow) * NH + lg * 8;
    uint4 bnx[3];
    #pragma unroll
    for (int nt = 0; nt < 3; ++nt) bnx[nt] = *(const uint4*)(w2base + nt * 16 * NH);
    #pragma unroll
    for (int kk = 0; kk < 6; ++kk) {
      uint4 bcur[3];
      #pragma unroll
      for (int nt = 0; nt < 3; ++nt) bcur[nt] = bnx[nt];
      if (kk < 5) {
        #pragma unroll
        for (int nt = 0; nt < 3; ++nt)
          bnx[nt] = *(const uint4*)(w2base + nt * 16 * NH + (kk + 1) * 32);
      }
      s16x8 am[8];
      #pragma unroll
      for (int mt = 0; mt < 8; ++mt)
        am[mt] = __builtin_bit_cast(s16x8,
                   *(const uint4*)(hbuf + (mt * 16 + lrow) * HROW + kk * 32 + lg * 8));
      #pragma unroll
      for (int mt = 0; mt < 8; ++mt)
        #pragma unroll
        for (int nt = 0; nt < 3; ++nt)
          acc2[mt][nt] = __builtin_amdgcn_mfma_f32_16x16x32_bf16(
              am[mt], __builtin_bit_cast(s16x8, bcur[nt]), acc2[mt][nt], 0, 0, 0);
    }
  }

  { // epilogue 2: mean over 16 rows of each C-tile (one supernode) + b2
    #pragma unroll
    for (int mt = 0; mt < 8; ++mt) {
      #pragma unroll
      for (int nt = 0; nt < 3; ++nt) {
        float ssum = acc2[mt][nt][0] + acc2[mt][nt][1] + acc2[mt][nt][2] + acc2[mt][nt][3];
        ssum += __shfl_xor(ssum, 16);
        ssum += __shfl_xor(ssum, 32);
        if (lane < 16) {
          int col = wave * 48 + nt * 16 + lrow;
          out[(size_t)(g * 8 + mt) * NH + col] = ssum * 0.0625f + b2v[col];
        }
      }
    }
  }
}

extern "C" void kernel_launch(void* const* d_in, const int* in_sizes, int n_in,
                              void* d_out, int out_size, void* d_ws, size_t ws_size,
                              hipStream_t stream) {
  (void)in_sizes; (void)n_in; (void)out_size; (void)ws_size;
  const float* pts  = (const float*)d_in[0];
  const int*   sidx = (const int*)d_in[1];
  const float* w_in = (const float*)d_in[2];
  const float* b_in = (const float*)d_in[3];
  const float* w1   = (const float*)d_in[4];
  const float* b1   = (const float*)d_in[5];
  const float* w2   = (const float*)d_in[6];
  const float* b2   = (const float*)d_in[7];
  float* out = (float*)d_out;

  u64* keys = (u64*)d_ws;                                       // 8192*32*8 = 2 MB
  uint16_t* wT1e = (uint16_t*)((char*)d_ws + (size_t)NB * NS * 32 * 8);
  uint16_t* wT2  = wT1e + NH * KP1;

  hipLaunchKernelGGL(prep_weights, dim3(NH), dim3(64), 0, stream,
                     w_in, b_in, w1, b1, w2, wT1e, wT2);

  hipLaunchKernelGGL(knn_kernel, dim3(NB * 64), dim3(512), 0, stream,
                     pts, sidx, keys);

  hipLaunchKernelGGL(mlp_kernel, dim3(NB * NS / 8), dim3(256), 0, stream,
                     pts, keys, b2, wT1e, wT2, out);
}

// Round 7
// 95.240 us; speedup vs baseline: 4.2340x; 1.1390x over previous
//
#include <hip/hip_runtime.h>
#include <stdint.h>

#define NB   8
#define NPTS 8192
#define NS   1024
#define NK   16
#define NH   192
#define KP1  224   // extended K for gemm1: 192 embed + 3 coords + 1 bias + 28 zero pad
#define HROW 232   // LDS row stride in bf16 elems (2-way max bank aliasing)
#define QTR  2048  // points per knn quarter-block

typedef float    f32x4 __attribute__((ext_vector_type(4)));
typedef short    s16x8 __attribute__((ext_vector_type(8)));
typedef uint32_t u32;
typedef unsigned long long u64;

// omega_m = 10000^(-m/32) = 10^(-m/8), exact table (folds to literals after unroll)
static __device__ const float OMEGA[32] = {
  1.0f, 0.74989420933245585f, 0.56234132519034907f, 0.42169650342858223f,
  0.31622776601683794f, 0.23713737056616552f, 0.17782794100389229f, 0.13335214321633237f,
  0.1f, 0.074989420933245585f, 0.056234132519034907f, 0.042169650342858223f,
  0.031622776601683794f, 0.023713737056616552f, 0.017782794100389229f, 0.013335214321633237f,
  0.01f, 0.0074989420933245585f, 0.0056234132519034907f, 0.0042169650342858223f,
  0.0031622776601683794f, 0.0023713737056616552f, 0.0017782794100389229f, 0.0013335214321633237f,
  0.001f, 0.00074989420933245585f, 0.00056234132519034907f, 0.00042169650342858223f,
  0.00031622776601683794f, 0.00023713737056616552f, 0.00017782794100389229f, 0.00013335214321633237f };

// exact RNE f32->bf16 (prep kernel only; perf-irrelevant there)
__device__ __forceinline__ uint16_t f2bf(float f) {
  u32 u = __float_as_uint(f);
  return (uint16_t)((u + 0x7FFFu + ((u >> 16) & 1u)) >> 16);
}
// fast pack of two f32 -> 2xbf16 in one u32, round-half-up (0.5ulp, ref is f32)
__device__ __forceinline__ u32 pk2bf(float f0, float f1) {
  return ((__float_as_uint(f0) + 0x8000u) >> 16) |
         ((__float_as_uint(f1) + 0x8000u) & 0xFFFF0000u);
}

// ---------------- kernel A: build extended transposed weights ----------------
__global__ void __launch_bounds__(64) prep_weights(
    const float* __restrict__ w_in, const float* __restrict__ b_in,
    const float* __restrict__ w1, const float* __restrict__ b1,
    const float* __restrict__ w2,
    uint16_t* __restrict__ wT1e, uint16_t* __restrict__ wT2) {
  const int n = blockIdx.x, t = threadIdx.x;
  float p0 = 0, p1 = 0, p2 = 0, pb = 0;
  #pragma unroll
  for (int kk = 0; kk < 3; ++kk) {
    int c = kk * 64 + t;
    float w1cn = w1[c * NH + n];
    wT1e[n * KP1 + c] = f2bf(w1cn);
    wT2 [n * NH  + c] = f2bf(w2[c * NH + n]);
    p0 = fmaf(w_in[0 * NH + c], w1cn, p0);
    p1 = fmaf(w_in[1 * NH + c], w1cn, p1);
    p2 = fmaf(w_in[2 * NH + c], w1cn, p2);
    pb = fmaf(b_in[c], w1cn, pb);
  }
  #pragma unroll
  for (int off = 32; off; off >>= 1) {
    p0 += __shfl_down(p0, off);
    p1 += __shfl_down(p1, off);
    p2 += __shfl_down(p2, off);
    pb += __shfl_down(pb, off);
  }
  if (t == 0) {
    wT1e[n * KP1 + 192] = f2bf(p0);
    wT1e[n * KP1 + 193] = f2bf(p1);
    wT1e[n * KP1 + 194] = f2bf(p2);
    wT1e[n * KP1 + 195] = f2bf(pb + b1[n]);
  }
  if (t >= 4 && t < 32) wT1e[n * KP1 + 192 + t] = 0;
}

// ---------------- kernel B: exact top-16 over a QUARTER of the points ----------------
// 2048 pts/block -> 24KB LDS -> 4 blocks/CU resident (grid 1024) -> 8 waves/SIMD.
// Emits the exact SORTED top-16 u64 keys of its quarter; mlp prologue merges 4 lists.
// Key = (bits(d)<<32)|global_idx: u64 order == (dist,idx) lex -> exact stable-top_k
// tie semantics, merge-invariant. Distances bit-identical to numpy f32 (no fma).
__global__ void __launch_bounds__(512, 8) knn_kernel(const float* __restrict__ pts,
                                                     const int* __restrict__ sidx,
                                                     u64* __restrict__ keys) {
  __shared__ float2 XY[QTR];   // 16 KB
  __shared__ float  Zs[QTR];   //  8 KB
  const int bid = blockIdx.x;
  const int b = bid >> 7;
  const int chunk = (bid >> 2) & 31;
  const int quarter = bid & 3;
  const int pbase = quarter * QTR;
  const float* pb = pts + ((size_t)b * NPTS + pbase) * 3;
  for (int i = threadIdx.x; i < QTR; i += 512) {
    XY[i] = float2{pb[3 * i], pb[3 * i + 1]};
    Zs[i] = pb[3 * i + 2];
  }
  __syncthreads();
  const int wave = threadIdx.x >> 6, lane = threadIdx.x & 63;
  const int sbase = chunk * 32 + wave * 4;

  float sx[4], sy[4], sz[4], minD[4], Td[4];
  u32 minI[4];
  u64 arr[4], T[4];
  #pragma unroll
  for (int q = 0; q < 4; ++q) {
    int si = sidx[b * NS + sbase + q];
    const float* qp = pts + ((size_t)b * NPTS + si) * 3;   // L2 broadcast
    sx[q] = qp[0]; sy[q] = qp[1]; sz[q] = qp[2];
    minD[q] = __uint_as_float(0x7F800000u);
    minI[q] = 0xFFFFFFFFu;
  }

  // ---- pass 1: lane-private minimum of each lane's 32-candidate column
  for (int t = 0; t < QTR / 64; ++t) {
    int lj = t * 64 + lane;
    float2 xy = XY[lj];
    float z = Zs[lj];
    #pragma unroll
    for (int q = 0; q < 4; ++q) {
      float dx = xy.x - sx[q], dy = xy.y - sy[q], dz = z - sz[q];
      float d = __fadd_rn(__fadd_rn(__fmul_rn(dx, dx), __fmul_rn(dy, dy)),
                          __fmul_rn(dz, dz));
      bool c = d < minD[q];            // strict: keeps lowest idx on exact ties
      minD[q] = c ? d : minD[q];
      minI[q] = c ? (u32)(pbase + lj) : minI[q];
    }
  }

  // ---- bitonic sort of the 64 per-lane minima (ascending across lanes)
  #pragma unroll
  for (int q = 0; q < 4; ++q) {
    u64 key = ((u64)__float_as_uint(minD[q]) << 32) | minI[q];
    #pragma unroll
    for (int k = 2; k <= 64; k <<= 1) {
      #pragma unroll
      for (int jj = k >> 1; jj > 0; jj >>= 1) {
        u64 p = __shfl_xor(key, jj);
        bool takeMin = (((lane & jj) == 0) == ((lane & k) == 0));
        key = (takeMin == (p < key)) ? p : key;
      }
    }
    arr[q] = (lane < 16) ? key : ~0ull;
    T[q] = __shfl(key, 15);                       // upper bound on true 16th key
    Td[q] = __uint_as_float((u32)(T[q] >> 32));
  }

  // ---- pass 2: exact insertion of the few candidates below the threshold
  for (int t = 0; t < QTR / 64; ++t) {
    int lj = t * 64 + lane;
    float2 xy = XY[lj];
    float z = Zs[lj];
    #pragma unroll
    for (int q = 0; q < 4; ++q) {
      float dx = xy.x - sx[q], dy = xy.y - sy[q], dz = z - sz[q];
      float d = __fadd_rn(__fadd_rn(__fmul_rn(dx, dx), __fmul_rn(dy, dy)),
                          __fmul_rn(dz, dz));
      u64 ball = __ballot(d <= Td[q] && (u32)(pbase + lj) != minI[q]);
      if (ball) {                                 // wave-uniform, rare
        u64 key = ((u64)__float_as_uint(d) << 32) | (u32)(pbase + lj);
        do {
          int src = __builtin_ctzll(ball);
          ball &= ball - 1;
          u64 k2 = __shfl(key, src);
          if (k2 < T[q]) {                        // exact (dist,idx) compare
            int r = __popcll(__ballot(arr[q] < k2));
            u64 up = __shfl_up(arr[q], 1);
            if (lane == r) arr[q] = k2;
            else if (lane > r && lane < 16) arr[q] = up;
            T[q] = __shfl(arr[q], 15);
            Td[q] = __uint_as_float((u32)(T[q] >> 32));
          }
        } while (ball);
      }
    }
  }
  #pragma unroll
  for (int q = 0; q < 4; ++q)
    if (lane < 16)
      keys[((size_t)(b * NS + sbase + q)) * 64 + quarter * 16 + lane] = arr[q];
}

// ---------------- kernel C: merge + gather + embed + MLP + mean-pool ----------------
__device__ __forceinline__ float h0ch(int c, const float crd[3]) {
  if (c >= 196) return 0.0f;
  if (c == 195) return 1.0f;          // bias channel
  if (c >= 192) return crd[c - 192];  // folded input-projection channels
  int dd = c >> 6, i = c & 63, m = i & 31;
  float arg = crd[dd] * OMEGA[m];
  return (i < 32) ? __sinf(arg) : __cosf(arg);
}

// gelu(x) = x * sigmoid(2u), u = 0.7978845608(x + 0.044715 x^3)
// -2u = -1.5957691216 * fma(0.044715x, x*x, x); rcp is v_rcp_f32 (~1ulp)
__device__ __forceinline__ float gelu_f(float x) {
  float v = -1.5957691216057308f * __fmaf_rn(0.044715f * x, x * x, x);
  return x * __builtin_amdgcn_rcpf(1.0f + __expf(v));
}

__global__ void __launch_bounds__(256) mlp_kernel(
    const float* __restrict__ pts, const u64* __restrict__ keys,
    const float* __restrict__ b2v,
    const uint16_t* __restrict__ wT1e, const uint16_t* __restrict__ wT2,
    float* __restrict__ out) {
  __shared__ uint16_t hbuf[128 * HROW];   // 59.4 KB -> 2 blocks/CU
  __shared__ int nbrL[128];
  const int g = blockIdx.x, tid = threadIdx.x;
  const int wave = tid >> 6, lane = tid & 63;
  const int lrow = lane & 15, lg = lane >> 4;

  // merge 4 sorted 16-lists per query: load lists 1,3 reversed -> two bitonic
  // 32-merges (lanes<32 asc, lanes>=32 desc) -> one 64-merge asc. Keys unique.
  #pragma unroll
  for (int ii = 0; ii < 2; ++ii) {
    int q = ii * 4 + wave;                     // query within block (0..7)
    int list = lane >> 4, pos = lane & 15;
    int rpos = (list & 1) ? (15 - pos) : pos;
    u64 key = keys[((size_t)g * 8 + q) * 64 + list * 16 + rpos];
    #pragma unroll
    for (int jj = 16; jj > 0; jj >>= 1) {
      u64 p = __shfl_xor(key, jj);
      bool takeMin = (((lane & jj) == 0) == ((lane & 32) == 0));
      key = (takeMin == (p < key)) ? p : key;
    }
    #pragma unroll
    for (int jj = 32; jj > 0; jj >>= 1) {
      u64 p = __shfl_xor(key, jj);
      bool takeMin = ((lane & jj) == 0);
      key = (takeMin == (p < key)) ? p : key;
    }
    if (lane < 16) nbrL[q * 16 + lane] = (int)(u32)key;
  }
  __syncthreads();

  { // h0 fill: [sincos embed | coords | 1 | zeros], 2 threads/row, uint2 stores
    int r = tid >> 1, half = tid & 1;
    int grow = g * 128 + r;
    int b = grow >> 14;
    int pidx = nbrL[r];
    const float* pp = pts + ((size_t)b * NPTS + pidx) * 3;
    float crd[3] = {pp[0], pp[1], pp[2]};
    #pragma unroll
    for (int jj = 0; jj < 28; ++jj) {
      int c = half * 112 + jj * 4;
      uint2 pk;
      pk.x = pk2bf(h0ch(c, crd),     h0ch(c + 1, crd));
      pk.y = pk2bf(h0ch(c + 2, crd), h0ch(c + 3, crd));
      *(uint2*)(hbuf + r * HROW + c) = pk;
    }
  }
  __syncthreads();

  // ---- gemm1 (SWAPPED operands): D1^T = wT1e-as-A x h0-as-B
  f32x4 acc1[3][8] = {};
  {
    const uint16_t* wbase = wT1e + (size_t)(wave * 48 + lrow) * KP1 + lg * 8;
    uint4 anx[3];
    #pragma unroll
    for (int nt = 0; nt < 3; ++nt) anx[nt] = *(const uint4*)(wbase + nt * 16 * KP1);
    #pragma unroll
    for (int kk = 0; kk < 7; ++kk) {
      uint4 acur[3];
      #pragma unroll
      for (int nt = 0; nt < 3; ++nt) acur[nt] = anx[nt];
      if (kk < 6) {
        #pragma unroll
        for (int nt = 0; nt < 3; ++nt)
          anx[nt] = *(const uint4*)(wbase + nt * 16 * KP1 + (kk + 1) * 32);
      }
      s16x8 bm[8];
      #pragma unroll
      for (int mt = 0; mt < 8; ++mt)
        bm[mt] = __builtin_bit_cast(s16x8,
                   *(const uint4*)(hbuf + (mt * 16 + lrow) * HROW + kk * 32 + lg * 8));
      #pragma unroll
      for (int nt = 0; nt < 3; ++nt)
        #pragma unroll
        for (int mt = 0; mt < 8; ++mt)
          acc1[nt][mt] = __builtin_amdgcn_mfma_f32_16x16x32_bf16(
              __builtin_bit_cast(s16x8, acur[nt]), bm[mt], acc1[nt][mt], 0, 0, 0);
    }
  }
  __syncthreads();   // all gemm1 reads of hbuf done before h1 overwrite

  { // epilogue 1: gelu (b1 folded), h1 write: 4 consecutive cols per b64 store
    #pragma unroll
    for (int nt = 0; nt < 3; ++nt) {
      #pragma unroll
      for (int mt = 0; mt < 8; ++mt) {
        uint2 pk;
        pk.x = pk2bf(gelu_f(acc1[nt][mt][0]), gelu_f(acc1[nt][mt][1]));
        pk.y = pk2bf(gelu_f(acc1[nt][mt][2]), gelu_f(acc1[nt][mt][3]));
        *(uint2*)(hbuf + (mt * 16 + lrow) * HROW + wave * 48 + nt * 16 + lg * 4) = pk;
      }
    }
  }
  __syncthreads();

  // ---- gemm2 (normal orientation): D2 = h1-as-A x wT2-as-B
  f32x4 acc2[8][3] = {};
  {
    const uint16_t* w2base = wT2 + (size_t)(wave * 48 + lrow) * NH + lg * 8;
    uint4 bnx[3];
    #pragma unroll
    for (int nt = 0; nt < 3; ++nt) bnx[nt] = *(const uint4*)(w2base + nt * 16 * NH);
    #pragma unroll
    for (int kk = 0; kk < 6; ++kk) {
      uint4 bcur[3];
      #pragma unroll
      for (int nt = 0; nt < 3; ++nt) bcur[nt] = bnx[nt];
      if (kk < 5) {
        #pragma unroll
        for (int nt = 0; nt < 3; ++nt)
          bnx[nt] = *(const uint4*)(w2base + nt * 16 * NH + (kk + 1) * 32);
      }
      s16x8 am[8];
      #pragma unroll
      for (int mt = 0; mt < 8; ++mt)
        am[mt] = __builtin_bit_cast(s16x8,
                   *(const uint4*)(hbuf + (mt * 16 + lrow) * HROW + kk * 32 + lg * 8));
      #pragma unroll
      for (int mt = 0; mt < 8; ++mt)
        #pragma unroll
        for (int nt = 0; nt < 3; ++nt)
          acc2[mt][nt] = __builtin_amdgcn_mfma_f32_16x16x32_bf16(
              am[mt], __builtin_bit_cast(s16x8, bcur[nt]), acc2[mt][nt], 0, 0, 0);
    }
  }

  { // epilogue 2: mean over 16 rows of each C-tile (one supernode) + b2
    #pragma unroll
    for (int mt = 0; mt < 8; ++mt) {
      #pragma unroll
      for (int nt = 0; nt < 3; ++nt) {
        float ssum = acc2[mt][nt][0] + acc2[mt][nt][1] + acc2[mt][nt][2] + acc2[mt][nt][3];
        ssum += __shfl_xor(ssum, 16);
        ssum += __shfl_xor(ssum, 32);
        if (lane < 16) {
          int col = wave * 48 + nt * 16 + lrow;
          out[(size_t)(g * 8 + mt) * NH + col] = ssum * 0.0625f + b2v[col];
        }
      }
    }
  }
}

extern "C" void kernel_launch(void* const* d_in, const int* in_sizes, int n_in,
                              void* d_out, int out_size, void* d_ws, size_t ws_size,
                              hipStream_t stream) {
  (void)in_sizes; (void)n_in; (void)out_size; (void)ws_size;
  const float* pts  = (const float*)d_in[0];
  const int*   sidx = (const int*)d_in[1];
  const float* w_in = (const float*)d_in[2];
  const float* b_in = (const float*)d_in[3];
  const float* w1   = (const float*)d_in[4];
  const float* b1   = (const float*)d_in[5];
  const float* w2   = (const float*)d_in[6];
  const float* b2   = (const float*)d_in[7];
  float* out = (float*)d_out;

  u64* keys = (u64*)d_ws;                                       // 8192*64*8 = 4 MB
  uint16_t* wT1e = (uint16_t*)((char*)d_ws + (size_t)NB * NS * 64 * 8);
  uint16_t* wT2  = wT1e + NH * KP1;

  hipLaunchKernelGGL(prep_weights, dim3(NH), dim3(64), 0, stream,
                     w_in, b_in, w1, b1, w2, wT1e, wT2);

  hipLaunchKernelGGL(knn_kernel, dim3(NB * 128), dim3(512), 0, stream,
                     pts, sidx, keys);

  hipLaunchKernelGGL(mlp_kernel, dim3(NB * NS / 8), dim3(256), 0, stream,
                     pts, keys, b2, wT1e, wT2, out);
}

// Round 8
// 90.557 us; speedup vs baseline: 4.4530x; 1.0517x over previous
//
#include <hip/hip_runtime.h>
#include <stdint.h>

#define NB   8
#define NPTS 8192
#define NS   1024
#define NK   16
#define NH   192
#define KP1  224   // extended K for gemm1: 192 embed + 3 coords + 1 bias + 28 zero pad
#define HROW 236   // LDS row stride in bf16 elems; 118 dw = 22 mod 32 -> conflict-free 16-row reads
#define QTR  2048  // points per knn quarter-block

typedef float    f32x4 __attribute__((ext_vector_type(4)));
typedef short    s16x8 __attribute__((ext_vector_type(8)));
typedef uint32_t u32;
typedef unsigned long long u64;

// omega_m = 10000^(-m/32) = 10^(-m/8); constexpr so literal indexing folds at compile time
constexpr float OMEGA[32] = {
  1.0f, 0.74989420933245585f, 0.56234132519034907f, 0.42169650342858223f,
  0.31622776601683794f, 0.23713737056616552f, 0.17782794100389229f, 0.13335214321633237f,
  0.1f, 0.074989420933245585f, 0.056234132519034907f, 0.042169650342858223f,
  0.031622776601683794f, 0.023713737056616552f, 0.017782794100389229f, 0.013335214321633237f,
  0.01f, 0.0074989420933245585f, 0.0056234132519034907f, 0.0042169650342858223f,
  0.0031622776601683794f, 0.0023713737056616552f, 0.0017782794100389229f, 0.0013335214321633237f,
  0.001f, 0.00074989420933245585f, 0.00056234132519034907f, 0.00042169650342858223f,
  0.00031622776601683794f, 0.00023713737056616552f, 0.00017782794100389229f, 0.00013335214321633237f };

// exact RNE f32->bf16 (prep kernel only)
__device__ __forceinline__ uint16_t f2bf(float f) {
  u32 u = __float_as_uint(f);
  return (uint16_t)((u + 0x7FFFu + ((u >> 16) & 1u)) >> 16);
}
// fast pack of two f32 -> 2xbf16, round-half-up (0.5ulp; ref is f32)
__device__ __forceinline__ u32 pk2bf(float f0, float f1) {
  return ((__float_as_uint(f0) + 0x8000u) >> 16) |
         ((__float_as_uint(f1) + 0x8000u) & 0xFFFF0000u);
}

// ---------------- kernel A: build extended transposed weights ----------------
__global__ void __launch_bounds__(64) prep_weights(
    const float* __restrict__ w_in, const float* __restrict__ b_in,
    const float* __restrict__ w1, const float* __restrict__ b1,
    const float* __restrict__ w2,
    uint16_t* __restrict__ wT1e, uint16_t* __restrict__ wT2) {
  const int n = blockIdx.x, t = threadIdx.x;
  float p0 = 0, p1 = 0, p2 = 0, pb = 0;
  #pragma unroll
  for (int kk = 0; kk < 3; ++kk) {
    int c = kk * 64 + t;
    float w1cn = w1[c * NH + n];
    wT1e[n * KP1 + c] = f2bf(w1cn);
    wT2 [n * NH  + c] = f2bf(w2[c * NH + n]);
    p0 = fmaf(w_in[0 * NH + c], w1cn, p0);
    p1 = fmaf(w_in[1 * NH + c], w1cn, p1);
    p2 = fmaf(w_in[2 * NH + c], w1cn, p2);
    pb = fmaf(b_in[c], w1cn, pb);
  }
  #pragma unroll
  for (int off = 32; off; off >>= 1) {
    p0 += __shfl_down(p0, off);
    p1 += __shfl_down(p1, off);
    p2 += __shfl_down(p2, off);
    pb += __shfl_down(pb, off);
  }
  if (t == 0) {
    wT1e[n * KP1 + 192] = f2bf(p0);
    wT1e[n * KP1 + 193] = f2bf(p1);
    wT1e[n * KP1 + 194] = f2bf(p2);
    wT1e[n * KP1 + 195] = f2bf(pb + b1[n]);
  }
  if (t >= 4 && t < 32) wT1e[n * KP1 + 192 + t] = 0;
}

// ---------------- kernel B: exact top-16 over a QUARTER of the points ----------------
// Same two-pass scheme as r7; added: manual next-tile LDS prefetch in both passes.
__global__ void __launch_bounds__(512, 8) knn_kernel(const float* __restrict__ pts,
                                                     const int* __restrict__ sidx,
                                                     u64* __restrict__ keys) {
  __shared__ float2 XY[QTR];   // 16 KB
  __shared__ float  Zs[QTR];   //  8 KB
  const int bid = blockIdx.x;
  const int b = bid >> 7;
  const int chunk = (bid >> 2) & 31;
  const int quarter = bid & 3;
  const int pbase = quarter * QTR;
  const float* pb = pts + ((size_t)b * NPTS + pbase) * 3;
  for (int i = threadIdx.x; i < QTR; i += 512) {
    XY[i] = float2{pb[3 * i], pb[3 * i + 1]};
    Zs[i] = pb[3 * i + 2];
  }
  __syncthreads();
  const int wave = threadIdx.x >> 6, lane = threadIdx.x & 63;
  const int sbase = chunk * 32 + wave * 4;

  float sx[4], sy[4], sz[4], minD[4], Td[4];
  u32 minI[4];
  u64 arr[4], T[4];
  #pragma unroll
  for (int q = 0; q < 4; ++q) {
    int si = sidx[b * NS + sbase + q];
    const float* qp = pts + ((size_t)b * NPTS + si) * 3;   // L2 broadcast
    sx[q] = qp[0]; sy[q] = qp[1]; sz[q] = qp[2];
    minD[q] = __uint_as_float(0x7F800000u);
    minI[q] = 0xFFFFFFFFu;
  }

  // ---- pass 1: lane-private minimum (next-tile prefetch covers LDS latency)
  {
    float2 xy = XY[lane];
    float  z  = Zs[lane];
    for (int t = 0; t < QTR / 64; ++t) {
      float2 xyc = xy; float zc = z;
      if (t + 1 < QTR / 64) { xy = XY[(t + 1) * 64 + lane]; z = Zs[(t + 1) * 64 + lane]; }
      int lj = t * 64 + lane;
      #pragma unroll
      for (int q = 0; q < 4; ++q) {
        float dx = xyc.x - sx[q], dy = xyc.y - sy[q], dz = zc - sz[q];
        float d = __fadd_rn(__fadd_rn(__fmul_rn(dx, dx), __fmul_rn(dy, dy)),
                            __fmul_rn(dz, dz));
        bool c = d < minD[q];            // strict: keeps lowest idx on exact ties
        minD[q] = c ? d : minD[q];
        minI[q] = c ? (u32)(pbase + lj) : minI[q];
      }
    }
  }

  // ---- bitonic sort of the 64 per-lane minima (ascending across lanes)
  #pragma unroll
  for (int q = 0; q < 4; ++q) {
    u64 key = ((u64)__float_as_uint(minD[q]) << 32) | minI[q];
    #pragma unroll
    for (int k = 2; k <= 64; k <<= 1) {
      #pragma unroll
      for (int jj = k >> 1; jj > 0; jj >>= 1) {
        u64 p = __shfl_xor(key, jj);
        bool takeMin = (((lane & jj) == 0) == ((lane & k) == 0));
        key = (takeMin == (p < key)) ? p : key;
      }
    }
    arr[q] = (lane < 16) ? key : ~0ull;
    T[q] = __shfl(key, 15);                       // upper bound on true 16th key
    Td[q] = __uint_as_float((u32)(T[q] >> 32));
  }

  // ---- pass 2: exact insertion of the few candidates below the threshold
  {
    float2 xy = XY[lane];
    float  z  = Zs[lane];
    for (int t = 0; t < QTR / 64; ++t) {
      float2 xyc = xy; float zc = z;
      if (t + 1 < QTR / 64) { xy = XY[(t + 1) * 64 + lane]; z = Zs[(t + 1) * 64 + lane]; }
      int lj = t * 64 + lane;
      #pragma unroll
      for (int q = 0; q < 4; ++q) {
        float dx = xyc.x - sx[q], dy = xyc.y - sy[q], dz = zc - sz[q];
        float d = __fadd_rn(__fadd_rn(__fmul_rn(dx, dx), __fmul_rn(dy, dy)),
                            __fmul_rn(dz, dz));
        u64 ball = __ballot(d <= Td[q] && (u32)(pbase + lj) != minI[q]);
        if (ball) {                                 // wave-uniform, rare
          u64 key = ((u64)__float_as_uint(d) << 32) | (u32)(pbase + lj);
          do {
            int src = __builtin_ctzll(ball);
            ball &= ball - 1;
            u64 k2 = __shfl(key, src);
            if (k2 < T[q]) {                        // exact (dist,idx) compare
              int r = __popcll(__ballot(arr[q] < k2));
              u64 up = __shfl_up(arr[q], 1);
              if (lane == r) arr[q] = k2;
              else if (lane > r && lane < 16) arr[q] = up;
              T[q] = __shfl(arr[q], 15);
              Td[q] = __uint_as_float((u32)(T[q] >> 32));
            }
          } while (ball);
        }
      }
    }
  }
  #pragma unroll
  for (int q = 0; q < 4; ++q)
    if (lane < 16)
      keys[((size_t)(b * NS + sbase + q)) * 64 + quarter * 16 + lane] = arr[q];
}

// ---------------- kernel C: merge + gather + embed + MLP + mean-pool ----------------
// h0ch is only ever called with COMPILE-TIME c now (two static half-loops below):
// all branches, OMEGA[m], crd[dd], sin/cos select fold to straight-line code.
__device__ __forceinline__ float h0ch(int c, float c0, float c1, float c2) {
  if (c >= 196) return 0.0f;
  if (c == 195) return 1.0f;          // bias channel
  if (c == 192) return c0;
  if (c == 193) return c1;
  if (c == 194) return c2;
  int dd = c >> 6, i = c & 63, m = i & 31;
  float coord = (dd == 0) ? c0 : ((dd == 1) ? c1 : c2);
  float arg = coord * OMEGA[m];
  return (i < 32) ? __sinf(arg) : __cosf(arg);
}

// gelu(x) = x * sigmoid(2u), u = 0.7978845608(x + 0.044715 x^3)
__device__ __forceinline__ float gelu_f(float x) {
  float v = -1.5957691216057308f * __fmaf_rn(0.044715f * x, x * x, x);
  return x * __builtin_amdgcn_rcpf(1.0f + __expf(v));
}

__global__ void __launch_bounds__(256) mlp_kernel(
    const float* __restrict__ pts, const u64* __restrict__ keys,
    const float* __restrict__ b2v,
    const uint16_t* __restrict__ wT1e, const uint16_t* __restrict__ wT2,
    float* __restrict__ out) {
  __shared__ uint16_t hbuf[128 * HROW];   // 60.4 KB -> 2 blocks/CU
  __shared__ int nbrL[128];
  const int g = blockIdx.x, tid = threadIdx.x;
  const int wave = tid >> 6, lane = tid & 63;
  const int lrow = lane & 15, lg = lane >> 4;

  // merge 4 sorted 16-lists per query: lists 1,3 loaded reversed -> two bitonic
  // 32-merges (lanes<32 asc, lanes>=32 desc) -> one 64-merge asc. Keys unique.
  #pragma unroll
  for (int ii = 0; ii < 2; ++ii) {
    int q = ii * 4 + wave;                     // query within block (0..7)
    int list = lane >> 4, pos = lane & 15;
    int rpos = (list & 1) ? (15 - pos) : pos;
    u64 key = keys[((size_t)g * 8 + q) * 64 + list * 16 + rpos];
    #pragma unroll
    for (int jj = 16; jj > 0; jj >>= 1) {
      u64 p = __shfl_xor(key, jj);
      bool takeMin = (((lane & jj) == 0) == ((lane & 32) == 0));
      key = (takeMin == (p < key)) ? p : key;
    }
    #pragma unroll
    for (int jj = 32; jj > 0; jj >>= 1) {
      u64 p = __shfl_xor(key, jj);
      bool takeMin = ((lane & jj) == 0);
      key = (takeMin == (p < key)) ? p : key;
    }
    if (lane < 16) nbrL[q * 16 + lane] = (int)(u32)key;
  }
  __syncthreads();

  { // h0 fill: two fully-static unrolled halves (c is a literal everywhere)
    int r = tid >> 1, half = tid & 1;
    int grow = g * 128 + r;
    int b = grow >> 14;
    int pidx = nbrL[r];
    const float* pp = pts + ((size_t)b * NPTS + pidx) * 3;
    float c0 = pp[0], c1 = pp[1], c2 = pp[2];
    if (half == 0) {
      #pragma unroll
      for (int jj = 0; jj < 28; ++jj) {
        const int c = jj * 4;
        uint2 pk;
        pk.x = pk2bf(h0ch(c,     c0, c1, c2), h0ch(c + 1, c0, c1, c2));
        pk.y = pk2bf(h0ch(c + 2, c0, c1, c2), h0ch(c + 3, c0, c1, c2));
        *(uint2*)(hbuf + r * HROW + c) = pk;
      }
    } else {
      #pragma unroll
      for (int jj = 0; jj < 28; ++jj) {
        const int c = 112 + jj * 4;
        uint2 pk;
        pk.x = pk2bf(h0ch(c,     c0, c1, c2), h0ch(c + 1, c0, c1, c2));
        pk.y = pk2bf(h0ch(c + 2, c0, c1, c2), h0ch(c + 3, c0, c1, c2));
        *(uint2*)(hbuf + r * HROW + c) = pk;
      }
    }
  }
  __syncthreads();

  // ---- gemm1 (SWAPPED operands): D1^T = wT1e-as-A x h0-as-B
  f32x4 acc1[3][8] = {};
  {
    const uint16_t* wbase = wT1e + (size_t)(wave * 48 + lrow) * KP1 + lg * 8;
    uint4 anx[3];
    #pragma unroll
    for (int nt = 0; nt < 3; ++nt) anx[nt] = *(const uint4*)(wbase + nt * 16 * KP1);
    #pragma unroll
    for (int kk = 0; kk < 7; ++kk) {
      uint4 acur[3];
      #pragma unroll
      for (int nt = 0; nt < 3; ++nt) acur[nt] = anx[nt];
      if (kk < 6) {
        #pragma unroll
        for (int nt = 0; nt < 3; ++nt)
          anx[nt] = *(const uint4*)(wbase + nt * 16 * KP1 + (kk + 1) * 32);
      }
      s16x8 bm[8];
      #pragma unroll
      for (int mt = 0; mt < 8; ++mt)
        bm[mt] = __builtin_bit_cast(s16x8,
                   *(const uint4*)(hbuf + (mt * 16 + lrow) * HROW + kk * 32 + lg * 8));
      #pragma unroll
      for (int nt = 0; nt < 3; ++nt)
        #pragma unroll
        for (int mt = 0; mt < 8; ++mt)
          acc1[nt][mt] = __builtin_amdgcn_mfma_f32_16x16x32_bf16(
              __builtin_bit_cast(s16x8, acur[nt]), bm[mt], acc1[nt][mt], 0, 0, 0);
    }
  }
  __syncthreads();   // all gemm1 reads of hbuf done before h1 overwrite

  { // epilogue 1: gelu (b1 folded), h1 write: 4 consecutive cols per b64 store
    #pragma unroll
    for (int nt = 0; nt < 3; ++nt) {
      #pragma unroll
      for (int mt = 0; mt < 8; ++mt) {
        uint2 pk;
        pk.x = pk2bf(gelu_f(acc1[nt][mt][0]), gelu_f(acc1[nt][mt][1]));
        pk.y = pk2bf(gelu_f(acc1[nt][mt][2]), gelu_f(acc1[nt][mt][3]));
        *(uint2*)(hbuf + (mt * 16 + lrow) * HROW + wave * 48 + nt * 16 + lg * 4) = pk;
      }
    }
  }
  __syncthreads();

  // ---- gemm2 (normal orientation): D2 = h1-as-A x wT2-as-B
  f32x4 acc2[8][3] = {};
  {
    const uint16_t* w2base = wT2 + (size_t)(wave * 48 + lrow) * NH + lg * 8;
    uint4 bnx[3];
    #pragma unroll
    for (int nt = 0; nt < 3; ++nt) bnx[nt] = *(const uint4*)(w2base + nt * 16 * NH);
    #pragma unroll
    for (int kk = 0; kk < 6; ++kk) {
      uint4 bcur[3];
      #pragma unroll
      for (int nt = 0; nt < 3; ++nt) bcur[nt] = bnx[nt];
      if (kk < 5) {
        #pragma unroll
        for (int nt = 0; nt < 3; ++nt)
          bnx[nt] = *(const uint4*)(w2base + nt * 16 * NH + (kk + 1) * 32);
      }
      s16x8 am[8];
      #pragma unroll
      for (int mt = 0; mt < 8; ++mt)
        am[mt] = __builtin_bit_cast(s16x8,
                   *(const uint4*)(hbuf + (mt * 16 + lrow) * HROW + kk * 32 + lg * 8));
      #pragma unroll
      for (int mt = 0; mt < 8; ++mt)
        #pragma unroll
        for (int nt = 0; nt < 3; ++nt)
          acc2[mt][nt] = __builtin_amdgcn_mfma_f32_16x16x32_bf16(
              am[mt], __builtin_bit_cast(s16x8, bcur[nt]), acc2[mt][nt], 0, 0, 0);
    }
  }

  { // epilogue 2: mean over 16 rows of each C-tile (one supernode) + b2
    #pragma unroll
    for (int mt = 0; mt < 8; ++mt) {
      #pragma unroll
      for (int nt = 0; nt < 3; ++nt) {
        float ssum = acc2[mt][nt][0] + acc2[mt][nt][1] + acc2[mt][nt][2] + acc2[mt][nt][3];
        ssum += __shfl_xor(ssum, 16);
        ssum += __shfl_xor(ssum, 32);
        if (lane < 16) {
          int col = wave * 48 + nt * 16 + lrow;
          out[(size_t)(g * 8 + mt) * NH + col] = ssum * 0.0625f + b2v[col];
        }
      }
    }
  }
}

extern "C" void kernel_launch(void* const* d_in, const int* in_sizes, int n_in,
                              void* d_out, int out_size, void* d_ws, size_t ws_size,
                              hipStream_t stream) {
  (void)in_sizes; (void)n_in; (void)out_size; (void)ws_size;
  const float* pts  = (const float*)d_in[0];
  const int*   sidx = (const int*)d_in[1];
  const float* w_in = (const float*)d_in[2];
  const float* b_in = (const float*)d_in[3];
  const float* w1   = (const float*)d_in[4];
  const float* b1   = (const float*)d_in[5];
  const float* w2   = (const float*)d_in[6];
  const float* b2   = (const float*)d_in[7];
  float* out = (float*)d_out;

  u64* keys = (u64*)d_ws;                                       // 8192*64*8 = 4 MB
  uint16_t* wT1e = (uint16_t*)((char*)d_ws + (size_t)NB * NS * 64 * 8);
  uint16_t* wT2  = wT1e + NH * KP1;

  hipLaunchKernelGGL(prep_weights, dim3(NH), dim3(64), 0, stream,
                     w_in, b_in, w1, b1, w2, wT1e, wT2);

  hipLaunchKernelGGL(knn_kernel, dim3(NB * 128), dim3(512), 0, stream,
                     pts, sidx, keys);

  hipLaunchKernelGGL(mlp_kernel, dim3(NB * NS / 8), dim3(256), 0, stream,
                     pts, keys, b2, wT1e, wT2, out);
}